// Round 1
// baseline (421.564 us; speedup 1.0000x reference)
//
#include <hip/hip_runtime.h>

#define B_    8
#define C_    64
#define O_    64
#define H_    128
#define W_    128
#define HW_   (H_ * W_)
#define NOFF_ 18   // 2*K*K offset channels
#define KK_   9    // K*K

// ---------------------------------------------------------------------------
// Weight transposes so the hot inner loops read wave-uniform CONTIGUOUS rows.
// w2   [(c*9+kk)][o]  <- w_conv[o][c][ky][kx]
// woff2[(c*9+ij)][m]  <- w_off[m][c][i][j]
// ---------------------------------------------------------------------------
__global__ __launch_bounds__(256) void prep_weights(
    const float* __restrict__ w_conv, const float* __restrict__ w_off,
    float* __restrict__ w2, float* __restrict__ woff2)
{
    int idx = blockIdx.x * blockDim.x + threadIdx.x;
    if (idx < O_ * 576) {               // 576 = C_*9
        int o = idx / 576, r = idx % 576;
        w2[r * O_ + o] = w_conv[idx];
    }
    if (idx < NOFF_ * 576) {
        int m = idx / 576, r = idx % 576;
        woff2[r * NOFF_ + m] = w_off[idx];
    }
}

// ---------------------------------------------------------------------------
// Offset conv: standard 3x3/pad1 conv, 18 out channels. 1 thread per pixel.
// ---------------------------------------------------------------------------
__global__ __launch_bounds__(256) void offset_conv(
    const float* __restrict__ x, const float* __restrict__ woff2,
    const float* __restrict__ b_off, float* __restrict__ offs)
{
    int idx = blockIdx.x * blockDim.x + threadIdx.x;  // b*HW + h*W + w
    int b  = idx >> 14;
    int hw = idx & (HW_ - 1);
    int h  = hw >> 7;
    int w  = hw & (W_ - 1);

    float acc[NOFF_];
#pragma unroll
    for (int m = 0; m < NOFF_; ++m) acc[m] = b_off[m];

    const float* xb = x + (size_t)b * C_ * HW_;
#pragma unroll 1
    for (int c = 0; c < C_; ++c) {
        const float* xc = xb + c * HW_;
#pragma unroll
        for (int i = 0; i < 3; ++i) {
            int yy = h - 1 + i;
            bool vy = (unsigned)yy < (unsigned)H_;
#pragma unroll
            for (int j = 0; j < 3; ++j) {
                int xx = w - 1 + j;
                bool v = vy && ((unsigned)xx < (unsigned)W_);
                float xv = v ? xc[yy * W_ + xx] : 0.0f;
                const float* wr = woff2 + (c * 9 + i * 3 + j) * NOFF_;
#pragma unroll
                for (int m = 0; m < NOFF_; ++m)
                    acc[m] = fmaf(xv, wr[m], acc[m]);
            }
        }
    }
    float* op = offs + (size_t)b * NOFF_ * HW_ + hw;
#pragma unroll
    for (int m = 0; m < NOFF_; ++m) op[m * HW_] = acc[m];
}

// ---------------------------------------------------------------------------
// Deformable conv: 1 thread per output pixel, acc[64] output channels in VGPRs.
// Bilinear sampling with per-corner validity (weights zeroed OOB, clamped idx),
// matching the reference's valid-mask * clip(gather) semantics exactly.
// ---------------------------------------------------------------------------
__global__ __launch_bounds__(256) void deform_conv(
    const float* __restrict__ x, const float* __restrict__ offs,
    const float* __restrict__ w2, float* __restrict__ out)
{
    int idx = blockIdx.x * blockDim.x + threadIdx.x;
    int b  = idx >> 14;
    int hw = idx & (HW_ - 1);
    int h  = hw >> 7;
    int w  = hw & (W_ - 1);

    float acc[O_];
#pragma unroll
    for (int o = 0; o < O_; ++o) acc[o] = 0.0f;

    const float* xb = x    + (size_t)b * C_ * HW_;
    const float* ob = offs + (size_t)b * NOFF_ * HW_ + hw;

#pragma unroll 1
    for (int kk = 0; kk < KK_; ++kk) {
        int ky = kk / 3, kx = kk % 3;
        float dy = ob[(2 * kk) * HW_];
        float dx = ob[(2 * kk + 1) * HW_];
        float py = (float)(h - 1 + ky) + dy;
        float px = (float)(w - 1 + kx) + dx;
        float y0f = floorf(py), x0f = floorf(px);
        float ly = py - y0f, lx = px - x0f;
        int y0 = (int)y0f, x0 = (int)x0f;

        float w00 = (1.0f - ly) * (1.0f - lx);
        float w01 = (1.0f - ly) * lx;
        float w10 = ly * (1.0f - lx);
        float w11 = ly * lx;

        bool vy0 = (unsigned)y0        < (unsigned)H_;
        bool vy1 = (unsigned)(y0 + 1)  < (unsigned)H_;
        bool vx0 = (unsigned)x0        < (unsigned)W_;
        bool vx1 = (unsigned)(x0 + 1)  < (unsigned)W_;
        if (!(vy0 && vx0)) w00 = 0.0f;
        if (!(vy0 && vx1)) w01 = 0.0f;
        if (!(vy1 && vx0)) w10 = 0.0f;
        if (!(vy1 && vx1)) w11 = 0.0f;

        int yc0 = min(max(y0, 0), H_ - 1);
        int yc1 = min(max(y0 + 1, 0), H_ - 1);
        int xc0 = min(max(x0, 0), W_ - 1);
        int xc1 = min(max(x0 + 1, 0), W_ - 1);
        int i00 = yc0 * W_ + xc0, i01 = yc0 * W_ + xc1;
        int i10 = yc1 * W_ + xc0, i11 = yc1 * W_ + xc1;

        const float* wk = w2 + kk * O_;   // row base for (c=0, kk)
#pragma unroll 1
        for (int c = 0; c < C_; ++c) {
            const float* xc = xb + c * HW_;
            float v00 = xc[i00], v01 = xc[i01];
            float v10 = xc[i10], v11 = xc[i11];
            float val = v00 * w00 + v01 * w01 + v10 * w10 + v11 * w11;
            const float* wr = wk + c * (KK_ * O_);  // uniform address -> s_load
#pragma unroll
            for (int o = 0; o < O_; ++o)
                acc[o] = fmaf(val, wr[o], acc[o]);
        }
    }

    float* outp = out + (size_t)b * O_ * HW_ + hw;
#pragma unroll
    for (int o = 0; o < O_; ++o) outp[o * HW_] = acc[o];
}

// ---------------------------------------------------------------------------
extern "C" void kernel_launch(void* const* d_in, const int* in_sizes, int n_in,
                              void* d_out, int out_size, void* d_ws, size_t ws_size,
                              hipStream_t stream)
{
    const float* x      = (const float*)d_in[0];
    const float* w_off  = (const float*)d_in[1];
    const float* b_off  = (const float*)d_in[2];
    const float* w_conv = (const float*)d_in[3];
    float* out = (float*)d_out;

    // workspace layout (bytes):
    //   w2    : [0,       147456)   576*64 f32
    //   woff2 : [147456,  188928)   576*18 f32
    //   offs  : [188928,  9626112)  8*18*128*128 f32
    char* ws = (char*)d_ws;
    float* w2    = (float*)(ws);
    float* woff2 = (float*)(ws + 147456);
    float* offs  = (float*)(ws + 188928);

    prep_weights<<<(O_ * 576 + 255) / 256, 256, 0, stream>>>(w_conv, w_off, w2, woff2);

    int npix = B_ * HW_;  // 131072
    offset_conv<<<npix / 256, 256, 0, stream>>>(x, woff2, b_off, offs);
    deform_conv<<<npix / 256, 256, 0, stream>>>(x, offs, w2, out);
}

// Round 2
// 139.511 us; speedup vs baseline: 3.0217x; 3.0217x over previous
//
#include <hip/hip_runtime.h>

#define B_    8
#define C_    64
#define O_    64
#define H_    128
#define W_    128
#define HW_   (H_ * W_)
#define NOFF_ 18
#define KK_   9

typedef __attribute__((ext_vector_type(8))) short  short8v;   // 8 x bf16 bits
typedef __attribute__((ext_vector_type(4))) float  f32x4;
typedef unsigned int uint32;
typedef unsigned short ushort;

__device__ __forceinline__ float bf2f(short s) {
    return __uint_as_float(((uint32)(ushort)s) << 16);
}
__device__ __forceinline__ ushort f2bf(float f) {   // RNE
    uint32 u = __float_as_uint(f);
    u += 0x7FFF + ((u >> 16) & 1);
    return (ushort)(u >> 16);
}

// ===========================================================================
// NEW PATH (bf16 NHWC + MFMA)
// ===========================================================================

// x [b][c][hw] f32  ->  xT [b][hw][c] bf16   (LDS tile transpose)
__global__ __launch_bounds__(256) void transpose_x(
    const float* __restrict__ x, ushort* __restrict__ xT)
{
    __shared__ float tile[64][65];
    int blk = blockIdx.x;
    int b   = blk >> 8;
    int hw0 = (blk & 255) * 64;
    int t   = threadIdx.x;
    int q   = t >> 6;       // 0..3
    int ln  = t & 63;
#pragma unroll
    for (int p = 0; p < 16; ++p) {
        int c = p * 4 + q;
        tile[c][ln] = x[((size_t)(b * C_ + c) << 14) + hw0 + ln];
    }
    __syncthreads();
#pragma unroll
    for (int p = 0; p < 16; ++p) {
        int hw = p * 4 + q;
        xT[(((size_t)b << 14) + hw0 + hw) * 64 + ln] = f2bf(tile[ln][hw]);
    }
}

// wfrag[kk][kc][nb][lane][i] bf16  <- w_conv[o][c][ky][kx]
//   c = kc*32 + (lane>>4)*8 + i ; o = nb*16 + (lane&15) ; kk = ky*3+kx
// woff2n[(ij*64+c)*18 + m] f32    <- w_off[m][c][ij]
__global__ __launch_bounds__(256) void prep_new(
    const float* __restrict__ w_conv, const float* __restrict__ w_off,
    ushort* __restrict__ wfrag, float* __restrict__ woff2n)
{
    int idx = blockIdx.x * blockDim.x + threadIdx.x;
    if (idx < 36864) {
        int i    = idx & 7;
        int lane = (idx >> 3) & 63;
        int nb   = (idx >> 9) & 3;
        int kc   = (idx >> 11) & 1;
        int kk   = idx >> 12;
        int c = kc * 32 + ((lane >> 4) << 3) + i;
        int o = nb * 16 + (lane & 15);
        wfrag[idx] = f2bf(w_conv[(o * C_ + c) * 9 + kk]);
    }
    if (idx < 10368) {
        int m  = idx % 18;
        int rc = idx / 18;          // ij*64 + c
        int ij = rc >> 6, c = rc & 63;
        woff2n[idx] = w_off[(m * C_ + c) * 9 + ij];
    }
}

// offset conv from xT (bf16 NHWC), f32 accumulate, 1 thread/pixel
__global__ __launch_bounds__(256) void offset_conv2(
    const ushort* __restrict__ xT, const float* __restrict__ woff2n,
    const float* __restrict__ b_off, float* __restrict__ offs)
{
    int idx = blockIdx.x * blockDim.x + threadIdx.x;
    int b  = idx >> 14;
    int hw = idx & (HW_ - 1);
    int h  = hw >> 7;
    int w  = hw & (W_ - 1);

    float acc[NOFF_];
#pragma unroll
    for (int m = 0; m < NOFF_; ++m) acc[m] = b_off[m];

    const ushort* xb = xT + ((size_t)b << 14) * 64;
#pragma unroll
    for (int ky = 0; ky < 3; ++ky) {
#pragma unroll
        for (int kx = 0; kx < 3; ++kx) {
            int yy = h - 1 + ky, xx = w - 1 + kx;
            if ((unsigned)yy < (unsigned)H_ && (unsigned)xx < (unsigned)W_) {
                const ushort* xp = xb + ((yy << 7) + xx) * 64;
                const float*  wp = woff2n + (ky * 3 + kx) * 64 * NOFF_;
#pragma unroll 1
                for (int c8 = 0; c8 < 8; ++c8) {
                    short8v v = *(const short8v*)(xp + c8 * 8);
#pragma unroll
                    for (int j = 0; j < 8; ++j) {
                        float xv = bf2f(v[j]);
                        const float* wr = wp + (c8 * 8 + j) * NOFF_;
#pragma unroll
                        for (int m = 0; m < NOFF_; ++m)
                            acc[m] = fmaf(xv, wr[m], acc[m]);
                    }
                }
            }
        }
    }
    float* op = offs + (size_t)b * NOFF_ * HW_ + hw;
#pragma unroll
    for (int m = 0; m < NOFF_; ++m) op[m * HW_] = acc[m];
}

// fused bilinear sampling (f32 from bf16) + MFMA contraction
// block: 256 thr = 4 waves; tile = 64 px (one b), all 64 o; K = 9kk x 64c
__global__ __launch_bounds__(256) void deform_mfma(
    const ushort* __restrict__ xT, const float* __restrict__ offs,
    const ushort* __restrict__ wfrag, float* __restrict__ out)
{
    __shared__ ushort val[64 * 64];     // 8 KB, XOR-swizzled [px][c] bf16
    char* valc = (char*)val;

    int blk  = blockIdx.x;
    int b    = blk & 7;                 // XCD-aligned batch
    int hw0  = (blk >> 3) * 64;
    int t    = threadIdx.x;
    int lane = t & 63;
    int wv   = t >> 6;

    // sampling role
    int px_s = t >> 2;
    int cg   = t & 3;                   // 16-channel group
    int hw_s = hw0 + px_s;
    int h_s  = hw_s >> 7;
    int w_s  = hw_s & (W_ - 1);
    const float*  ob = offs + (size_t)b * NOFF_ * HW_ + hw_s;
    const ushort* xb = xT + ((size_t)b << 14) * 64;

    f32x4 acc[4];
#pragma unroll
    for (int nb = 0; nb < 4; ++nb) acc[nb] = (f32x4){0.f, 0.f, 0.f, 0.f};

#pragma unroll
    for (int ky = 0; ky < 3; ++ky) {
#pragma unroll
        for (int kx = 0; kx < 3; ++kx) {
            const int kk = ky * 3 + kx;
            // ---- sample 16 channels of one pixel into LDS ----
            float dy = ob[(2 * kk) * HW_];
            float dx = ob[(2 * kk + 1) * HW_];
            float py = (float)(h_s - 1 + ky) + dy;
            float px = (float)(w_s - 1 + kx) + dx;
            float y0f = floorf(py), x0f = floorf(px);
            float ly = py - y0f, lx = px - x0f;
            int y0 = (int)y0f, x0 = (int)x0f;

            float w00 = (1.f - ly) * (1.f - lx);
            float w01 = (1.f - ly) * lx;
            float w10 = ly * (1.f - lx);
            float w11 = ly * lx;
            bool vy0 = (unsigned)y0       < (unsigned)H_;
            bool vy1 = (unsigned)(y0 + 1) < (unsigned)H_;
            bool vx0 = (unsigned)x0       < (unsigned)W_;
            bool vx1 = (unsigned)(x0 + 1) < (unsigned)W_;
            if (!(vy0 && vx0)) w00 = 0.f;
            if (!(vy0 && vx1)) w01 = 0.f;
            if (!(vy1 && vx0)) w10 = 0.f;
            if (!(vy1 && vx1)) w11 = 0.f;
            int yc0 = min(max(y0, 0), H_ - 1);
            int yc1 = min(max(y0 + 1, 0), H_ - 1);
            int xc0 = min(max(x0, 0), W_ - 1);
            int xc1 = min(max(x0 + 1, 0), W_ - 1);
            const ushort* p00 = xb + ((yc0 << 7) + xc0) * 64 + cg * 16;
            const ushort* p01 = xb + ((yc0 << 7) + xc1) * 64 + cg * 16;
            const ushort* p10 = xb + ((yc1 << 7) + xc0) * 64 + cg * 16;
            const ushort* p11 = xb + ((yc1 << 7) + xc1) * 64 + cg * 16;
            short8v q00a = *(const short8v*)p00, q00b = *(const short8v*)(p00 + 8);
            short8v q01a = *(const short8v*)p01, q01b = *(const short8v*)(p01 + 8);
            short8v q10a = *(const short8v*)p10, q10b = *(const short8v*)(p10 + 8);
            short8v q11a = *(const short8v*)p11, q11b = *(const short8v*)(p11 + 8);

            short8v pk0, pk1;
#pragma unroll
            for (int j = 0; j < 8; ++j) {
                float ra = fmaf(bf2f(q00a[j]), w00,
                           fmaf(bf2f(q01a[j]), w01,
                           fmaf(bf2f(q10a[j]), w10, bf2f(q11a[j]) * w11)));
                float rb = fmaf(bf2f(q00b[j]), w00,
                           fmaf(bf2f(q01b[j]), w01,
                           fmaf(bf2f(q10b[j]), w10, bf2f(q11b[j]) * w11)));
                pk0[j] = (short)f2bf(ra);
                pk1[j] = (short)f2bf(rb);
            }
            int base = (px_s << 7) + (cg << 5);
            int sw   = (px_s & 7) << 4;
            *(short8v*)(valc + ((base) ^ sw))      = pk0;
            *(short8v*)(valc + ((base + 16) ^ sw)) = pk1;

            __syncthreads();
            // ---- MFMA: wave wv does px rows [16wv,16wv+16) x all 64 o ----
#pragma unroll
            for (int kc = 0; kc < 2; ++kc) {
                int row  = (wv << 4) + (lane & 15);
                int colb = (kc << 6) + ((lane >> 4) << 4);
                short8v af = *(const short8v*)(valc + row * 128 + (colb ^ ((row & 7) << 4)));
#pragma unroll
                for (int nb = 0; nb < 4; ++nb) {
                    const short8v bfr = *(const short8v*)(wfrag +
                        ((((kk * 2 + kc) << 2) + nb) << 9) + (lane << 3));
                    acc[nb] = __builtin_amdgcn_mfma_f32_16x16x32_bf16(af, bfr, acc[nb], 0, 0, 0);
                }
            }
            __syncthreads();
        }
    }

    // epilogue: D layout col=lane&15 (o), row=(lane>>4)*4+reg (px)
#pragma unroll
    for (int nb = 0; nb < 4; ++nb) {
        int o = nb * 16 + (lane & 15);
        float* outp = out + ((size_t)(b * O_ + o) << 14) + hw0 + (wv << 4) + ((lane >> 4) << 2);
#pragma unroll
        for (int r = 0; r < 4; ++r) outp[r] = acc[nb][r];
    }
}

// ===========================================================================
// FALLBACK PATH (round-1 f32, used when ws_size is too small)
// ===========================================================================
__global__ __launch_bounds__(256) void prep_weights(
    const float* __restrict__ w_conv, const float* __restrict__ w_off,
    float* __restrict__ w2, float* __restrict__ woff2)
{
    int idx = blockIdx.x * blockDim.x + threadIdx.x;
    if (idx < O_ * 576) { int o = idx / 576, r = idx % 576; w2[r * O_ + o] = w_conv[idx]; }
    if (idx < NOFF_ * 576) { int m = idx / 576, r = idx % 576; woff2[r * NOFF_ + m] = w_off[idx]; }
}

__global__ __launch_bounds__(256) void offset_conv(
    const float* __restrict__ x, const float* __restrict__ woff2,
    const float* __restrict__ b_off, float* __restrict__ offs)
{
    int idx = blockIdx.x * blockDim.x + threadIdx.x;
    int b = idx >> 14, hw = idx & (HW_ - 1), h = hw >> 7, w = hw & (W_ - 1);
    float acc[NOFF_];
#pragma unroll
    for (int m = 0; m < NOFF_; ++m) acc[m] = b_off[m];
    const float* xb = x + (size_t)b * C_ * HW_;
#pragma unroll 1
    for (int c = 0; c < C_; ++c) {
        const float* xc = xb + c * HW_;
#pragma unroll
        for (int i = 0; i < 3; ++i) {
            int yy = h - 1 + i;
            bool vy = (unsigned)yy < (unsigned)H_;
#pragma unroll
            for (int j = 0; j < 3; ++j) {
                int xx = w - 1 + j;
                bool v = vy && ((unsigned)xx < (unsigned)W_);
                float xv = v ? xc[yy * W_ + xx] : 0.0f;
                const float* wr = woff2 + (c * 9 + i * 3 + j) * NOFF_;
#pragma unroll
                for (int m = 0; m < NOFF_; ++m) acc[m] = fmaf(xv, wr[m], acc[m]);
            }
        }
    }
    float* op = offs + (size_t)b * NOFF_ * HW_ + hw;
#pragma unroll
    for (int m = 0; m < NOFF_; ++m) op[m * HW_] = acc[m];
}

__global__ __launch_bounds__(256) void deform_conv(
    const float* __restrict__ x, const float* __restrict__ offs,
    const float* __restrict__ w2, float* __restrict__ out)
{
    int idx = blockIdx.x * blockDim.x + threadIdx.x;
    int b = idx >> 14, hw = idx & (HW_ - 1), h = hw >> 7, w = hw & (W_ - 1);
    float acc[O_];
#pragma unroll
    for (int o = 0; o < O_; ++o) acc[o] = 0.0f;
    const float* xb = x + (size_t)b * C_ * HW_;
    const float* ob = offs + (size_t)b * NOFF_ * HW_ + hw;
#pragma unroll 1
    for (int kk = 0; kk < KK_; ++kk) {
        int ky = kk / 3, kx = kk % 3;
        float dy = ob[(2 * kk) * HW_], dx = ob[(2 * kk + 1) * HW_];
        float py = (float)(h - 1 + ky) + dy;
        float px = (float)(w - 1 + kx) + dx;
        float y0f = floorf(py), x0f = floorf(px);
        float ly = py - y0f, lx = px - x0f;
        int y0 = (int)y0f, x0 = (int)x0f;
        float w00 = (1.f - ly) * (1.f - lx), w01 = (1.f - ly) * lx;
        float w10 = ly * (1.f - lx), w11 = ly * lx;
        bool vy0 = (unsigned)y0 < (unsigned)H_, vy1 = (unsigned)(y0 + 1) < (unsigned)H_;
        bool vx0 = (unsigned)x0 < (unsigned)W_, vx1 = (unsigned)(x0 + 1) < (unsigned)W_;
        if (!(vy0 && vx0)) w00 = 0.f;
        if (!(vy0 && vx1)) w01 = 0.f;
        if (!(vy1 && vx0)) w10 = 0.f;
        if (!(vy1 && vx1)) w11 = 0.f;
        int yc0 = min(max(y0, 0), H_ - 1), yc1 = min(max(y0 + 1, 0), H_ - 1);
        int xc0 = min(max(x0, 0), W_ - 1), xc1 = min(max(x0 + 1, 0), W_ - 1);
        int i00 = yc0 * W_ + xc0, i01 = yc0 * W_ + xc1;
        int i10 = yc1 * W_ + xc0, i11 = yc1 * W_ + xc1;
        const float* wk = w2 + kk * O_;
#pragma unroll 1
        for (int c = 0; c < C_; ++c) {
            const float* xc = xb + c * HW_;
            float val = xc[i00] * w00 + xc[i01] * w01 + xc[i10] * w10 + xc[i11] * w11;
            const float* wr = wk + c * (KK_ * O_);
#pragma unroll
            for (int o = 0; o < O_; ++o) acc[o] = fmaf(val, wr[o], acc[o]);
        }
    }
    float* outp = out + (size_t)b * O_ * HW_ + hw;
#pragma unroll
    for (int o = 0; o < O_; ++o) outp[o * HW_] = acc[o];
}

// ===========================================================================
extern "C" void kernel_launch(void* const* d_in, const int* in_sizes, int n_in,
                              void* d_out, int out_size, void* d_ws, size_t ws_size,
                              hipStream_t stream)
{
    const float* x      = (const float*)d_in[0];
    const float* w_off  = (const float*)d_in[1];
    const float* b_off  = (const float*)d_in[2];
    const float* w_conv = (const float*)d_in[3];
    float* out = (float*)d_out;
    char* ws = (char*)d_ws;

    const size_t XT_OFF    = 0;                    // 16,777,216 B (bf16 NHWC)
    const size_t OFFS_OFF  = 16777216;             //  9,437,184 B (f32)
    const size_t WFRAG_OFF = 26214400;             //     73,728 B
    const size_t WOFF_OFF  = 26288128;             //     41,472 B
    const size_t NEED      = 26329600;

    int npix = B_ * HW_;                            // 131072

    if (ws_size >= NEED) {
        ushort* xT     = (ushort*)(ws + XT_OFF);
        float*  offs   = (float*)(ws + OFFS_OFF);
        ushort* wfrag  = (ushort*)(ws + WFRAG_OFF);
        float*  woff2n = (float*)(ws + WOFF_OFF);

        transpose_x <<<2048, 256, 0, stream>>>(x, xT);
        prep_new    <<<144, 256, 0, stream>>>(w_conv, w_off, wfrag, woff2n);
        offset_conv2<<<npix / 256, 256, 0, stream>>>(xT, woff2n, b_off, offs);
        deform_mfma <<<2048, 256, 0, stream>>>(xT, offs, wfrag, out);
    } else {
        float* w2    = (float*)(ws);
        float* woff2 = (float*)(ws + 147456);
        float* offs  = (float*)(ws + 188928);
        prep_weights<<<(O_ * 576 + 255) / 256, 256, 0, stream>>>(w_conv, w_off, w2, woff2);
        offset_conv <<<npix / 256, 256, 0, stream>>>(x, woff2, b_off, offs);
        deform_conv <<<npix / 256, 256, 0, stream>>>(x, offs, w2, out);
    }
}

// Round 3
// 134.953 us; speedup vs baseline: 3.1238x; 1.0338x over previous
//
#include <hip/hip_runtime.h>
#include <hip/hip_bf16.h>

#define B_    8
#define C_    64
#define O_    64
#define H_    128
#define W_    128
#define HW_   (H_ * W_)
#define NOFF_ 18
#define KK_   9

typedef __attribute__((ext_vector_type(8))) short  short8v;   // 8 x bf16 bits (16B)
typedef __attribute__((ext_vector_type(4))) unsigned int u32x4;
typedef __attribute__((ext_vector_type(4))) float  f32x4;
typedef unsigned int uint32;
typedef unsigned short ushort;

__device__ __forceinline__ float bf2f(short s) {
    return __uint_as_float(((uint32)(ushort)s) << 16);
}
__device__ __forceinline__ ushort f2bf(float f) {   // RNE
    uint32 u = __float_as_uint(f);
    u += 0x7FFF + ((u >> 16) & 1);
    return (ushort)(u >> 16);
}
// unpack a bf16 pair (one dword) to two f32: 2 VALU ops for 2 values
__device__ __forceinline__ void unpk(uint32 q, float& lo, float& hi) {
    lo = __uint_as_float(q << 16);
    hi = __uint_as_float(q & 0xFFFF0000u);
}
// pack two f32 -> bf16x2 dword (v_cvt_pk_bf16_f32 via intrinsic)
__device__ __forceinline__ uint32 pkbf(float lo, float hi) {
    __hip_bfloat162 b2 = __float22bfloat162_rn(make_float2(lo, hi));
    union { __hip_bfloat162 b; uint32 u; } cv; cv.b = b2; return cv.u;
}

// ---------------------------------------------------------------------------
// x [b][c][hw] f32  ->  xT [b][hw][c] bf16  (LDS tile transpose; proven R2)
// ---------------------------------------------------------------------------
__global__ __launch_bounds__(256) void transpose_x(
    const float* __restrict__ x, ushort* __restrict__ xT)
{
    __shared__ float tile[64][65];
    int blk = blockIdx.x;
    int b   = blk >> 8;
    int hw0 = (blk & 255) * 64;
    int t   = threadIdx.x;
    int q   = t >> 6;
    int ln  = t & 63;
#pragma unroll
    for (int p = 0; p < 16; ++p) {
        int c = p * 4 + q;
        tile[c][ln] = x[((size_t)(b * C_ + c) << 14) + hw0 + ln];
    }
    __syncthreads();
#pragma unroll
    for (int p = 0; p < 16; ++p) {
        int hw = p * 4 + q;
        xT[(((size_t)b << 14) + hw0 + hw) * 64 + ln] = f2bf(tile[ln][hw]);
    }
}

// ---------------------------------------------------------------------------
// Weight fragment prep.
// wfrag[kk][kc][nb(4)][lane][i] bf16 <- w_conv : c=kc*32+(lane>>4)*8+i, o=nb*16+(lane&15)
// whi/wlo[kk][kc][nb(2)][lane][i]    <- w_off hi/lo bf16 split, m=nb*16+(lane&15) (0 for m>=18)
// ---------------------------------------------------------------------------
__global__ __launch_bounds__(256) void prep2(
    const float* __restrict__ w_conv, const float* __restrict__ w_off,
    ushort* __restrict__ wfrag, ushort* __restrict__ whi, ushort* __restrict__ wlo)
{
    int idx = blockIdx.x * 256 + threadIdx.x;
    if (idx < 36864) {
        int i    = idx & 7;
        int lane = (idx >> 3) & 63;
        int nb   = (idx >> 9) & 3;
        int kc   = (idx >> 11) & 1;
        int kk   = idx >> 12;
        int c = kc * 32 + ((lane >> 4) << 3) + i;
        int o = nb * 16 + (lane & 15);
        wfrag[idx] = f2bf(w_conv[(o * C_ + c) * 9 + kk]);
    }
    if (idx < 18432) {
        int i    = idx & 7;
        int lane = (idx >> 3) & 63;
        int nb   = (idx >> 9) & 1;
        int kc   = (idx >> 10) & 1;
        int kk   = idx >> 11;
        int m = nb * 16 + (lane & 15);
        int c = kc * 32 + ((lane >> 4) << 3) + i;
        float wv_ = (m < NOFF_) ? w_off[(m * C_ + c) * 9 + kk] : 0.0f;
        ushort hi = f2bf(wv_);
        whi[idx] = hi;
        wlo[idx] = f2bf(wv_ - bf2f((short)hi));
    }
}

// ---------------------------------------------------------------------------
// Offset conv as pure MFMA (N padded 18->32, hi/lo bf16 weights = f32 quality).
// Barrier-free: each wave owns 16 px x 32 cols; A-fragments gathered directly
// from xT (fixed integer neighbor offsets). Offsets written f16 NHWC.
// ---------------------------------------------------------------------------
__global__ __launch_bounds__(256) void offconv_mfma(
    const ushort* __restrict__ xT, const ushort* __restrict__ whi,
    const ushort* __restrict__ wlo, const float* __restrict__ b_off,
    _Float16* __restrict__ offsh)
{
    int blk  = blockIdx.x;
    int b    = blk & 7;
    int hw0  = (blk >> 3) * 64;
    int t    = threadIdx.x;
    int lane = t & 63;
    int wv   = t >> 6;
    int pxb  = hw0 + wv * 16;
    int pr   = lane & 15;
    int g    = lane >> 4;
    int px   = pxb + pr;
    int h = px >> 7, w = px & (W_ - 1);
    const ushort* xb = xT + (((size_t)b << 14) << 6);

    f32x4 acc[2];
#pragma unroll
    for (int nb = 0; nb < 2; ++nb) acc[nb] = (f32x4){0.f, 0.f, 0.f, 0.f};

#pragma unroll
    for (int kk = 0; kk < KK_; ++kk) {
        int ky = kk / 3, kx = kk % 3;
        int yy = h - 1 + ky, xx = w - 1 + kx;
        bool valid = ((unsigned)yy < (unsigned)H_) && ((unsigned)xx < (unsigned)W_);
        int src = (min(max(yy, 0), H_ - 1) << 7) + min(max(xx, 0), W_ - 1);
#pragma unroll
        for (int kc = 0; kc < 2; ++kc) {
            int c0 = kc * 32 + g * 8;
            short8v a = *(const short8v*)(xb + ((size_t)src << 6) + c0);
            short8v z = {};
            a = valid ? a : z;
#pragma unroll
            for (int nb = 0; nb < 2; ++nb) {
                const ushort* base = whi + ((((kk * 2 + kc) * 2) + nb) << 9) + (lane << 3);
                short8v bh = *(const short8v*)base;
                short8v bl = *(const short8v*)(wlo + ((((kk * 2 + kc) * 2) + nb) << 9) + (lane << 3));
                acc[nb] = __builtin_amdgcn_mfma_f32_16x16x32_bf16(a, bh, acc[nb], 0, 0, 0);
                acc[nb] = __builtin_amdgcn_mfma_f32_16x16x32_bf16(a, bl, acc[nb], 0, 0, 0);
            }
        }
    }

    // C/D: col=lane&15 -> m, row=(lane>>4)*4+r -> px
#pragma unroll
    for (int nb = 0; nb < 2; ++nb) {
        int m = nb * 16 + pr;
        if (m < NOFF_) {
            float bias = b_off[m];
#pragma unroll
            for (int r = 0; r < 4; ++r) {
                int prow = pxb + g * 4 + r;
                offsh[(size_t)((b << 14) + prow) * NOFF_ + m] = (_Float16)(acc[nb][r] + bias);
            }
        }
    }
}

// ---------------------------------------------------------------------------
// Deformable conv: barrier-free, LDS-free. Each lane gathers its OWN MFMA
// A-fragment (8 contiguous channels at 4 bilinear corners), bilerps in f32
// registers, repacks bf16, feeds MFMA. Wave = 16 px x 64 o.
// ---------------------------------------------------------------------------
__global__ __launch_bounds__(256) void deform_mfma2(
    const ushort* __restrict__ xT, const _Float16* __restrict__ offsh,
    const ushort* __restrict__ wfrag, float* __restrict__ out)
{
    int blk  = blockIdx.x;
    int b    = blk & 7;                 // XCD-aligned batch
    int hw0  = (blk >> 3) * 64;
    int t    = threadIdx.x;
    int lane = t & 63;
    int wv   = t >> 6;
    int pxb  = hw0 + wv * 16;
    int pr   = lane & 15;               // px row within wave tile (A-frag row)
    int g    = lane >> 4;               // k-group (A-frag k = g*8+i)
    int px   = pxb + pr;
    int h = px >> 7, w = px & (W_ - 1);
    const ushort* xb = xT + (((size_t)b << 14) << 6);

    // hoist all 9 offset pairs (f16x2 dword loads)
    const uint32* obu = (const uint32*)(offsh + (size_t)((b << 14) + px) * NOFF_);
    float dy[9], dx[9];
#pragma unroll
    for (int kk = 0; kk < 9; ++kk) {
        union { uint32 u; _Float16 h2[2]; } cv; cv.u = obu[kk];
        dy[kk] = (float)cv.h2[0];
        dx[kk] = (float)cv.h2[1];
    }

    f32x4 acc[4];
#pragma unroll
    for (int nb = 0; nb < 4; ++nb) acc[nb] = (f32x4){0.f, 0.f, 0.f, 0.f};

#pragma unroll 3
    for (int kk = 0; kk < KK_; ++kk) {
        int ky = kk / 3, kx = kk % 3;
        float py  = (float)(h - 1 + ky) + dy[kk];
        float pxf = (float)(w - 1 + kx) + dx[kk];
        float y0f = floorf(py), x0f = floorf(pxf);
        float ly = py - y0f, lx = pxf - x0f;
        int y0 = (int)y0f, x0 = (int)x0f;

        float w00 = (1.f - ly) * (1.f - lx);
        float w01 = (1.f - ly) * lx;
        float w10 = ly * (1.f - lx);
        float w11 = ly * lx;
        bool vy0 = (unsigned)y0       < (unsigned)H_;
        bool vy1 = (unsigned)(y0 + 1) < (unsigned)H_;
        bool vx0 = (unsigned)x0       < (unsigned)W_;
        bool vx1 = (unsigned)(x0 + 1) < (unsigned)W_;
        if (!(vy0 && vx0)) w00 = 0.f;
        if (!(vy0 && vx1)) w01 = 0.f;
        if (!(vy1 && vx0)) w10 = 0.f;
        if (!(vy1 && vx1)) w11 = 0.f;
        int yc0 = min(max(y0, 0), H_ - 1);
        int yc1 = min(max(y0 + 1, 0), H_ - 1);
        int xc0 = min(max(x0, 0), W_ - 1);
        int xc1 = min(max(x0 + 1, 0), W_ - 1);
        int b00 = (yc0 << 7) + xc0, b01 = (yc0 << 7) + xc1;
        int b10 = (yc1 << 7) + xc0, b11 = (yc1 << 7) + xc1;

#pragma unroll
        for (int kc = 0; kc < 2; ++kc) {
            int c0 = kc * 32 + g * 8;
            u32x4 q00 = *(const u32x4*)(xb + ((size_t)b00 << 6) + c0);
            u32x4 q01 = *(const u32x4*)(xb + ((size_t)b01 << 6) + c0);
            u32x4 q10 = *(const u32x4*)(xb + ((size_t)b10 << 6) + c0);
            u32x4 q11 = *(const u32x4*)(xb + ((size_t)b11 << 6) + c0);

            short8v a;
            uint32* au = (uint32*)&a;
#pragma unroll
            for (int p = 0; p < 4; ++p) {
                float l00, h00, l01, h01, l10, h10, l11, h11;
                unpk(q00[p], l00, h00);
                unpk(q01[p], l01, h01);
                unpk(q10[p], l10, h10);
                unpk(q11[p], l11, h11);
                float rl = fmaf(l00, w00, fmaf(l01, w01, fmaf(l10, w10, l11 * w11)));
                float rh = fmaf(h00, w00, fmaf(h01, w01, fmaf(h10, w10, h11 * w11)));
                au[p] = pkbf(rl, rh);
            }
#pragma unroll
            for (int nb = 0; nb < 4; ++nb) {
                short8v bfr = *(const short8v*)(wfrag +
                    ((((kk * 2 + kc) << 2) + nb) << 9) + (lane << 3));
                acc[nb] = __builtin_amdgcn_mfma_f32_16x16x32_bf16(a, bfr, acc[nb], 0, 0, 0);
            }
        }
    }

    // C/D: col=lane&15 -> o, row=(lane>>4)*4+r -> px
#pragma unroll
    for (int nb = 0; nb < 4; ++nb) {
        int o = nb * 16 + pr;
        float* outp = out + (((size_t)(b * O_ + o)) << 14) + pxb + (g << 2);
#pragma unroll
        for (int r = 0; r < 4; ++r) outp[r] = acc[nb][r];
    }
}

// ===========================================================================
extern "C" void kernel_launch(void* const* d_in, const int* in_sizes, int n_in,
                              void* d_out, int out_size, void* d_ws, size_t ws_size,
                              hipStream_t stream)
{
    const float* x      = (const float*)d_in[0];
    const float* w_off  = (const float*)d_in[1];
    const float* b_off  = (const float*)d_in[2];
    const float* w_conv = (const float*)d_in[3];
    float* out = (float*)d_out;
    char* ws = (char*)d_ws;

    // workspace layout (bytes) — total 21,643,264 (< proven-available 26.3 MB)
    const size_t XT_OFF    = 0;           // 16,777,216  bf16 NHWC x
    const size_t OFFS_OFF  = 16777216;    //  4,718,592  f16 NHWC offsets
    const size_t WFRAG_OFF = 21495808;    //     73,728  deform weight frags
    const size_t WHI_OFF   = 21569536;    //     36,864  offset weight hi
    const size_t WLO_OFF   = 21606400;    //     36,864  offset weight lo

    ushort*    xT    = (ushort*)(ws + XT_OFF);
    _Float16*  offsh = (_Float16*)(ws + OFFS_OFF);
    ushort*    wfrag = (ushort*)(ws + WFRAG_OFF);
    ushort*    whi   = (ushort*)(ws + WHI_OFF);
    ushort*    wlo   = (ushort*)(ws + WLO_OFF);

    transpose_x <<<2048, 256, 0, stream>>>(x, xT);
    prep2       <<<144, 256, 0, stream>>>(w_conv, w_off, wfrag, whi, wlo);
    offconv_mfma<<<2048, 256, 0, stream>>>(xT, whi, wlo, b_off, offsh);
    deform_mfma2<<<2048, 256, 0, stream>>>(xT, offsh, wfrag, out);
}

// Round 4
// 123.801 us; speedup vs baseline: 3.4052x; 1.0901x over previous
//
#include <hip/hip_runtime.h>

#define B_    8
#define C_    64
#define O_    64
#define H_    128
#define W_    128
#define HW_   (H_ * W_)
#define NOFF_ 18
#define KK_   9

typedef __attribute__((ext_vector_type(8))) _Float16 f16x8;
typedef __attribute__((ext_vector_type(2))) _Float16 f16x2;
typedef __attribute__((ext_vector_type(4))) unsigned int u32x4;
typedef __attribute__((ext_vector_type(4))) float f32x4;
typedef unsigned int uint32;
typedef unsigned short ushort;

__device__ __forceinline__ f16x2 u2h(uint32 u) {
    union { uint32 u; f16x2 h; } c; c.u = u; return c.h;
}
__device__ __forceinline__ f16x8 u2h8(u32x4 q) {
    union { u32x4 u; f16x8 h; } c; c.u = q; return c.h;
}

// ---------------------------------------------------------------------------
// x [b][c][hw] f32  ->  xT [b][hw][c] f16   (LDS tile transpose)
// ---------------------------------------------------------------------------
__global__ __launch_bounds__(256) void transpose_x(
    const float* __restrict__ x, _Float16* __restrict__ xT)
{
    __shared__ float tile[64][65];
    int blk = blockIdx.x;
    int b   = blk >> 8;
    int hw0 = (blk & 255) * 64;
    int t   = threadIdx.x;
    int q   = t >> 6;
    int ln  = t & 63;
#pragma unroll
    for (int p = 0; p < 16; ++p) {
        int c = p * 4 + q;
        tile[c][ln] = x[((size_t)(b * C_ + c) << 14) + hw0 + ln];
    }
    __syncthreads();
#pragma unroll
    for (int p = 0; p < 16; ++p) {
        int hw = p * 4 + q;
        xT[(((size_t)b << 14) + hw0 + hw) * 64 + ln] = (_Float16)tile[ln][hw];
    }
}

// ---------------------------------------------------------------------------
// Weight fragments (f16).
// wfrag[kk][kc][nb4][lane][i] <- w_conv : c=kc*32+(lane>>4)*8+i, o=nb*16+(lane&15)
// wofff[kk][kc][nb2][lane][i] <- w_off  : m=nb*16+(lane&15) (0 for m>=18)
// ---------------------------------------------------------------------------
__global__ __launch_bounds__(256) void prep3(
    const float* __restrict__ w_conv, const float* __restrict__ w_off,
    _Float16* __restrict__ wfrag, _Float16* __restrict__ wofff)
{
    int idx = blockIdx.x * 256 + threadIdx.x;
    if (idx < 36864) {
        int i    = idx & 7;
        int lane = (idx >> 3) & 63;
        int nb   = (idx >> 9) & 3;
        int kc   = (idx >> 11) & 1;
        int kk   = idx >> 12;
        int c = kc * 32 + ((lane >> 4) << 3) + i;
        int o = nb * 16 + (lane & 15);
        wfrag[idx] = (_Float16)w_conv[(o * C_ + c) * 9 + kk];
    }
    if (idx < 18432) {
        int i    = idx & 7;
        int lane = (idx >> 3) & 63;
        int nb   = (idx >> 9) & 1;
        int kc   = (idx >> 10) & 1;
        int kk   = idx >> 11;
        int m = nb * 16 + (lane & 15);
        int c = kc * 32 + ((lane >> 4) << 3) + i;
        wofff[idx] = (_Float16)((m < NOFF_) ? w_off[(m * C_ + c) * 9 + kk] : 0.0f);
    }
}

// ---------------------------------------------------------------------------
// Offset conv as MFMA (N 18->32), f16, 2-stage software-pipelined loads.
// ---------------------------------------------------------------------------
__global__ __launch_bounds__(256, 2) void offconv_mfma2(
    const _Float16* __restrict__ xT, const _Float16* __restrict__ wofff,
    const float* __restrict__ b_off, _Float16* __restrict__ offsh)
{
    int blk  = blockIdx.x;
    int b    = blk & 7;
    int hw0  = (blk >> 3) * 64;
    int t    = threadIdx.x;
    int lane = t & 63;
    int wv   = t >> 6;
    int pxb  = hw0 + wv * 16;
    int pr   = lane & 15;
    int g    = lane >> 4;
    int px   = pxb + pr;
    int h = px >> 7, w = px & (W_ - 1);
    const _Float16* xb = xT + (((size_t)b << 14) << 6);

    f32x4 acc[2];
#pragma unroll
    for (int nb = 0; nb < 2; ++nb) acc[nb] = (f32x4){0.f, 0.f, 0.f, 0.f};

    u32x4 xq[2][2];
    bool  vld[2];

    auto issueO = [&](int kk, int st) {
        int ky = kk / 3, kx = kk % 3;
        int yy = h - 1 + ky, xx = w - 1 + kx;
        vld[st] = ((unsigned)yy < (unsigned)H_) && ((unsigned)xx < (unsigned)W_);
        int src = (min(max(yy, 0), H_ - 1) << 7) + min(max(xx, 0), W_ - 1);
        const _Float16* p = xb + ((size_t)src << 6) + g * 8;
        xq[st][0] = *(const u32x4*)p;
        xq[st][1] = *(const u32x4*)(p + 32);
    };

    issueO(0, 0);
#pragma unroll
    for (int kk = 0; kk < KK_; ++kk) {
        const int s = kk & 1, n = s ^ 1;
        if (kk < KK_ - 1) issueO(kk + 1, n);
#pragma unroll
        for (int kc = 0; kc < 2; ++kc) {
            f16x8 a = u2h8(xq[s][kc]);
            f16x8 z = {};
            a = vld[s] ? a : z;
#pragma unroll
            for (int nb = 0; nb < 2; ++nb) {
                f16x8 bfr = *(const f16x8*)(wofff +
                    ((((kk * 2 + kc) << 1) + nb) << 9) + (lane << 3));
                acc[nb] = __builtin_amdgcn_mfma_f32_16x16x32_f16(a, bfr, acc[nb], 0, 0, 0);
            }
        }
    }

    // C/D: col=lane&15 -> m, row=(lane>>4)*4+r -> px
#pragma unroll
    for (int nb = 0; nb < 2; ++nb) {
        int m = nb * 16 + pr;
        if (m < NOFF_) {
            float bias = b_off[m];
#pragma unroll
            for (int r = 0; r < 4; ++r) {
                int prow = pxb + g * 4 + r;
                offsh[(size_t)((b << 14) + prow) * NOFF_ + m] = (_Float16)(acc[nb][r] + bias);
            }
        }
    }
}

// ---------------------------------------------------------------------------
// Deformable conv: LDS/barrier-free, f16, packed-f16 bilerp, 2-stage pipeline.
// Wave = 16 px x 64 o; lane gathers its own A-fragment (8 contiguous ch x 4
// corners), double-buffered so next kk's 8 gathers fly under this kk's MFMA.
// ---------------------------------------------------------------------------
__global__ __launch_bounds__(256, 2) void deform_mfma3(
    const _Float16* __restrict__ xT, const _Float16* __restrict__ offsh,
    const _Float16* __restrict__ wfrag, float* __restrict__ out)
{
    int blk  = blockIdx.x;
    int b    = blk & 7;                 // XCD-aligned batch
    int hw0  = (blk >> 3) * 64;
    int t    = threadIdx.x;
    int lane = t & 63;
    int wv   = t >> 6;
    int pxb  = hw0 + wv * 16;
    int pr   = lane & 15;
    int g    = lane >> 4;
    int px   = pxb + pr;
    int h = px >> 7, w = px & (W_ - 1);
    const _Float16* xb = xT + (((size_t)b << 14) << 6);

    // hoist all 9 offset pairs (f16x2 per kk)
    const uint32* obu = (const uint32*)(offsh + (size_t)((b << 14) + px) * NOFF_);
    uint32 dpk[9];
#pragma unroll
    for (int kk = 0; kk < 9; ++kk) dpk[kk] = obu[kk];

    f32x4 acc[4];
#pragma unroll
    for (int nb = 0; nb < 4; ++nb) acc[nb] = (f32x4){0.f, 0.f, 0.f, 0.f};

    u32x4 q[2][8];      // [stage][corner*2 + kc]
    f16x2 Wc[2][4];     // packed corner weights
    int   cb[2][4];     // corner element bases (hw index)

    auto prep = [&](int kk, int st) {
        union { uint32 u; f16x2 hh; } cv; cv.u = dpk[kk];
        float dyv = (float)cv.hh[0], dxv = (float)cv.hh[1];
        int ky = kk / 3, kx = kk % 3;
        float py  = (float)(h - 1 + ky) + dyv;
        float pxf = (float)(w - 1 + kx) + dxv;
        float y0f = floorf(py), x0f = floorf(pxf);
        float ly = py - y0f, lx = pxf - x0f;
        int y0 = (int)y0f, x0 = (int)x0f;
        float w00 = (1.f - ly) * (1.f - lx);
        float w01 = (1.f - ly) * lx;
        float w10 = ly * (1.f - lx);
        float w11 = ly * lx;
        bool vy0 = (unsigned)y0       < (unsigned)H_;
        bool vy1 = (unsigned)(y0 + 1) < (unsigned)H_;
        bool vx0 = (unsigned)x0       < (unsigned)W_;
        bool vx1 = (unsigned)(x0 + 1) < (unsigned)W_;
        if (!(vy0 && vx0)) w00 = 0.f;
        if (!(vy0 && vx1)) w01 = 0.f;
        if (!(vy1 && vx0)) w10 = 0.f;
        if (!(vy1 && vx1)) w11 = 0.f;
        int yc0 = min(max(y0, 0), H_ - 1);
        int yc1 = min(max(y0 + 1, 0), H_ - 1);
        int xc0 = min(max(x0, 0), W_ - 1);
        int xc1 = min(max(x0 + 1, 0), W_ - 1);
        cb[st][0] = (yc0 << 7) + xc0;
        cb[st][1] = (yc0 << 7) + xc1;
        cb[st][2] = (yc1 << 7) + xc0;
        cb[st][3] = (yc1 << 7) + xc1;
        Wc[st][0] = (f16x2){(_Float16)w00, (_Float16)w00};
        Wc[st][1] = (f16x2){(_Float16)w01, (_Float16)w01};
        Wc[st][2] = (f16x2){(_Float16)w10, (_Float16)w10};
        Wc[st][3] = (f16x2){(_Float16)w11, (_Float16)w11};
    };
    auto issue = [&](int st) {
#pragma unroll
        for (int cr = 0; cr < 4; ++cr) {
            const _Float16* p = xb + ((size_t)cb[st][cr] << 6) + g * 8;
            q[st][cr * 2 + 0] = *(const u32x4*)p;
            q[st][cr * 2 + 1] = *(const u32x4*)(p + 32);
        }
    };

    prep(0, 0);
    issue(0);
#pragma unroll
    for (int kk = 0; kk < KK_; ++kk) {
        const int s = kk & 1, n = s ^ 1;
        if (kk < KK_ - 1) { prep(kk + 1, n); issue(n); }
#pragma unroll
        for (int kc = 0; kc < 2; ++kc) {
            f16x8 a;
            f16x2* ap = (f16x2*)&a;
#pragma unroll
            for (int p = 0; p < 4; ++p) {
                ap[p] = u2h(q[s][0 + kc][p]) * Wc[s][0]
                      + u2h(q[s][2 + kc][p]) * Wc[s][1]
                      + u2h(q[s][4 + kc][p]) * Wc[s][2]
                      + u2h(q[s][6 + kc][p]) * Wc[s][3];
            }
#pragma unroll
            for (int nb = 0; nb < 4; ++nb) {
                f16x8 bfr = *(const f16x8*)(wfrag +
                    ((((kk * 2 + kc) << 2) + nb) << 9) + (lane << 3));
                acc[nb] = __builtin_amdgcn_mfma_f32_16x16x32_f16(a, bfr, acc[nb], 0, 0, 0);
            }
        }
    }

    // C/D: col=lane&15 -> o, row=(lane>>4)*4+r -> px ; 16B vector stores
#pragma unroll
    for (int nb = 0; nb < 4; ++nb) {
        int o = nb * 16 + pr;
        float* outp = out + (((size_t)(b * O_ + o)) << 14) + pxb + (g << 2);
        *(f32x4*)outp = acc[nb];
    }
}

// ===========================================================================
extern "C" void kernel_launch(void* const* d_in, const int* in_sizes, int n_in,
                              void* d_out, int out_size, void* d_ws, size_t ws_size,
                              hipStream_t stream)
{
    const float* x      = (const float*)d_in[0];
    const float* w_off  = (const float*)d_in[1];
    const float* b_off  = (const float*)d_in[2];
    const float* w_conv = (const float*)d_in[3];
    float* out = (float*)d_out;
    char* ws = (char*)d_ws;

    // workspace layout (bytes) — total 21,606,400+36,864 = 21,643,264
    const size_t XT_OFF    = 0;           // 16,777,216  f16 NHWC x
    const size_t OFFS_OFF  = 16777216;    //  4,718,592  f16 NHWC offsets
    const size_t WFRAG_OFF = 21495808;    //     73,728  deform weight frags
    const size_t WOFF_OFF  = 21569536;    //     36,864  offset weight frags

    _Float16* xT    = (_Float16*)(ws + XT_OFF);
    _Float16* offsh = (_Float16*)(ws + OFFS_OFF);
    _Float16* wfrag = (_Float16*)(ws + WFRAG_OFF);
    _Float16* wofff = (_Float16*)(ws + WOFF_OFF);

    transpose_x  <<<2048, 256, 0, stream>>>(x, xT);
    prep3        <<<144, 256, 0, stream>>>(w_conv, w_off, wfrag, wofff);
    offconv_mfma2<<<2048, 256, 0, stream>>>(xT, wofff, b_off, offsh);
    deform_mfma3 <<<2048, 256, 0, stream>>>(xT, offsh, wfrag, out);
}

// Round 5
// 107.204 us; speedup vs baseline: 3.9324x; 1.1548x over previous
//
#include <hip/hip_runtime.h>

#define B_    8
#define C_    64
#define O_    64
#define H_    128
#define W_    128
#define HW_   (H_ * W_)
#define NOFF_ 18
#define KK_   9

typedef __attribute__((ext_vector_type(8))) _Float16 f16x8;
typedef __attribute__((ext_vector_type(2))) _Float16 f16x2;
typedef __attribute__((ext_vector_type(4))) unsigned int u32x4;
typedef __attribute__((ext_vector_type(4))) float f32x4;
typedef unsigned int uint32;
typedef unsigned short ushort;

__device__ __forceinline__ f16x2 u2h(uint32 u) {
    union { uint32 u; f16x2 h; } c; c.u = u; return c.h;
}
__device__ __forceinline__ f16x8 u2h8(u32x4 q) {
    union { u32x4 u; f16x8 h; } c; c.u = q; return c.h;
}

// asm-pinned 16B global loads: volatile => compiler cannot sink/reorder them.
#define GLOAD16(dst, a64) \
    asm volatile("global_load_dwordx4 %0, %1, off" : "=v"(dst) : "v"(a64) : "memory")
#define GLOAD16O64(dst, a64) \
    asm volatile("global_load_dwordx4 %0, %1, off offset:64" : "=v"(dst) : "v"(a64) : "memory")
#define WAITV(N) do { \
    asm volatile("s_waitcnt vmcnt(" #N ")" ::: "memory"); \
    __builtin_amdgcn_sched_barrier(0); } while (0)

// ---------------------------------------------------------------------------
// x [b][c][hw] f32  ->  xT [b][hw][c] f16   (LDS tile transpose)
// ---------------------------------------------------------------------------
__global__ __launch_bounds__(256) void transpose_x(
    const float* __restrict__ x, _Float16* __restrict__ xT)
{
    __shared__ float tile[64][65];
    int blk = blockIdx.x;
    int b   = blk >> 8;
    int hw0 = (blk & 255) * 64;
    int t   = threadIdx.x;
    int q   = t >> 6;
    int ln  = t & 63;
#pragma unroll
    for (int p = 0; p < 16; ++p) {
        int c = p * 4 + q;
        tile[c][ln] = x[((size_t)(b * C_ + c) << 14) + hw0 + ln];
    }
    __syncthreads();
#pragma unroll
    for (int p = 0; p < 16; ++p) {
        int hw = p * 4 + q;
        xT[(((size_t)b << 14) + hw0 + hw) * 64 + ln] = (_Float16)tile[ln][hw];
    }
}

// ---------------------------------------------------------------------------
// Weight fragments (f16).
// wfrag[kk][kc][nb4][lane][i] <- w_conv : c=kc*32+(lane>>4)*8+i, o=nb*16+(lane&15)
// wofff[kk][kc][nb2][lane][i] <- w_off  : m=nb*16+(lane&15) (0 for m>=18)
// ---------------------------------------------------------------------------
__global__ __launch_bounds__(256) void prep3(
    const float* __restrict__ w_conv, const float* __restrict__ w_off,
    _Float16* __restrict__ wfrag, _Float16* __restrict__ wofff)
{
    int idx = blockIdx.x * 256 + threadIdx.x;
    if (idx < 36864) {
        int i    = idx & 7;
        int lane = (idx >> 3) & 63;
        int nb   = (idx >> 9) & 3;
        int kc   = (idx >> 11) & 1;
        int kk   = idx >> 12;
        int c = kc * 32 + ((lane >> 4) << 3) + i;
        int o = nb * 16 + (lane & 15);
        wfrag[idx] = (_Float16)w_conv[(o * C_ + c) * 9 + kk];
    }
    if (idx < 18432) {
        int i    = idx & 7;
        int lane = (idx >> 3) & 63;
        int nb   = (idx >> 9) & 1;
        int kc   = (idx >> 10) & 1;
        int kk   = idx >> 11;
        int m = nb * 16 + (lane & 15);
        int c = kc * 32 + ((lane >> 4) << 3) + i;
        wofff[idx] = (_Float16)((m < NOFF_) ? w_off[(m * C_ + c) * 9 + kk] : 0.0f);
    }
}

// ---------------------------------------------------------------------------
// Offset conv as MFMA, weights in LDS, asm-pinned gathers 3-deep (vmcnt(4)).
// ---------------------------------------------------------------------------
__global__ __launch_bounds__(256, 4) void offconv_mfma3(
    const _Float16* __restrict__ xT, const _Float16* __restrict__ wofff,
    const float* __restrict__ b_off, _Float16* __restrict__ offsh)
{
    __shared__ _Float16 wlds[18432];          // 36,864 B: all 9 kk offset-weight frags
    int t = threadIdx.x;
    {
        const u32x4* src = (const u32x4*)wofff;
        u32x4* dst = (u32x4*)wlds;
#pragma unroll
        for (int r = 0; r < 9; ++r) dst[r * 256 + t] = src[r * 256 + t];
    }
    __syncthreads();                          // drains all compiler VMEM (vmcnt(0))

    int blk  = blockIdx.x;
    int b    = blk & 7;
    int hw0  = (blk >> 3) * 64;
    int lane = t & 63;
    int wv   = t >> 6;
    int pxb  = hw0 + wv * 16;
    int pr   = lane & 15;
    int g    = lane >> 4;
    int px   = pxb + pr;
    int h = px >> 7, w = px & (W_ - 1);
    const _Float16* xb = xT + (((size_t)b << 14) << 6);

    f32x4 acc[2];
#pragma unroll
    for (int nb = 0; nb < 2; ++nb) acc[nb] = (f32x4){0.f, 0.f, 0.f, 0.f};

    u32x4 q[3][2];
    bool  vld[3];

    auto issueO = [&](int kk, int st) {
        int ky = kk / 3, kx = kk % 3;
        int yy = h - 1 + ky, xx = w - 1 + kx;
        vld[st] = ((unsigned)yy < (unsigned)H_) && ((unsigned)xx < (unsigned)W_);
        int src = (min(max(yy, 0), H_ - 1) << 7) + min(max(xx, 0), W_ - 1);
        unsigned long long a = (unsigned long long)(xb + ((size_t)src << 6) + g * 8);
        GLOAD16(q[st][0], a);
        GLOAD16O64(q[st][1], a);              // channels +32 = +64 B
    };

    issueO(0, 0); issueO(1, 1); issueO(2, 2);
#pragma unroll
    for (int kk = 0; kk < KK_; ++kk) {
        const int s = kk % 3;
        if (kk < 7)      { WAITV(4); }
        else if (kk < 8) { WAITV(2); }
        else             { WAITV(0); }
#pragma unroll
        for (int kc = 0; kc < 2; ++kc) {
            f16x8 a = u2h8(q[s][kc]);
            f16x8 z = {};
            a = vld[s] ? a : z;
#pragma unroll
            for (int nb = 0; nb < 2; ++nb) {
                f16x8 bfr = *(const f16x8*)(wlds +
                    ((((kk * 2 + kc) << 1) + nb) << 9) + (lane << 3));
                acc[nb] = __builtin_amdgcn_mfma_f32_16x16x32_f16(a, bfr, acc[nb], 0, 0, 0);
            }
        }
        if (kk < 6) issueO(kk + 3, s);        // reuse slot s after consumption
    }

    // C/D: col=lane&15 -> m, row=(lane>>4)*4+r -> px
#pragma unroll
    for (int nb = 0; nb < 2; ++nb) {
        int m = nb * 16 + pr;
        if (m < NOFF_) {
            float bias = b_off[m];
#pragma unroll
            for (int r = 0; r < 4; ++r) {
                int prow = pxb + g * 4 + r;
                offsh[(size_t)((b << 14) + prow) * NOFF_ + m] = (_Float16)(acc[nb][r] + bias);
            }
        }
    }
}

// ---------------------------------------------------------------------------
// Deformable conv: weights kk=0..7 in 64 KB LDS (kk=8 in VGPRs), asm-pinned
// gathers double-buffered with s_waitcnt vmcnt(8) — compiler cannot collapse.
// Wave = 16 px x 64 o, packed-f16 bilerp in registers, zero barriers in loop.
// ---------------------------------------------------------------------------
__global__ __launch_bounds__(256, 2) void deform_mfma4(
    const _Float16* __restrict__ xT, const _Float16* __restrict__ offsh,
    const _Float16* __restrict__ wfrag, float* __restrict__ out)
{
    __shared__ _Float16 wlds[32768];          // 65,536 B: frags (kk*2+kc)*4+nb for kk<8
    int t    = threadIdx.x;
    int blk  = blockIdx.x;
    int b    = blk & 7;                       // XCD-aligned batch
    int hw0  = (blk >> 3) * 64;
    int lane = t & 63;
    int wv   = t >> 6;
    int pxb  = hw0 + wv * 16;
    int pr   = lane & 15;
    int g    = lane >> 4;
    int px   = pxb + pr;
    int h = px >> 7, w = px & (W_ - 1);
    const _Float16* xb = xT + (((size_t)b << 14) << 6);

    // ---- ALL compiler VMEM happens before the barrier (clean vmcnt after) ----
    {
        const u32x4* src = (const u32x4*)wfrag;
        u32x4* dst = (u32x4*)wlds;
#pragma unroll
        for (int r = 0; r < 16; ++r) dst[r * 256 + t] = src[r * 256 + t];
    }
    // kk=8 weight frags -> registers (frag id 64+f, f = kc*4+nb)
    u32x4 wreg[8];
#pragma unroll
    for (int f = 0; f < 8; ++f)
        wreg[f] = *(const u32x4*)(wfrag + ((64 + f) << 9) + (lane << 3));
    // hoist 9 offset pairs
    const uint32* obu = (const uint32*)(offsh + (size_t)((b << 14) + px) * NOFF_);
    uint32 dpk[9];
#pragma unroll
    for (int kk = 0; kk < 9; ++kk) dpk[kk] = obu[kk];
    __syncthreads();                          // vmcnt(0)+lgkmcnt(0) drain

    f32x4 acc[4];
#pragma unroll
    for (int nb = 0; nb < 4; ++nb) acc[nb] = (f32x4){0.f, 0.f, 0.f, 0.f};

    u32x4 q[2][8];                            // [stage][corner*2 + kc]
    f16x2 Wc[2][4];                           // packed corner weights

    auto pi = [&](int kk, int st) {           // prep + issue (asm) for stage st
        union { uint32 u; f16x2 hh; } cv; cv.u = dpk[kk];
        float dyv = (float)cv.hh[0], dxv = (float)cv.hh[1];
        int ky = kk / 3, kx = kk % 3;
        float py  = (float)(h - 1 + ky) + dyv;
        float pxf = (float)(w - 1 + kx) + dxv;
        float y0f = floorf(py), x0f = floorf(pxf);
        float ly = py - y0f, lx = pxf - x0f;
        int y0 = (int)y0f, x0 = (int)x0f;
        float w00 = (1.f - ly) * (1.f - lx);
        float w01 = (1.f - ly) * lx;
        float w10 = ly * (1.f - lx);
        float w11 = ly * lx;
        bool vy0 = (unsigned)y0       < (unsigned)H_;
        bool vy1 = (unsigned)(y0 + 1) < (unsigned)H_;
        bool vx0 = (unsigned)x0       < (unsigned)W_;
        bool vx1 = (unsigned)(x0 + 1) < (unsigned)W_;
        if (!(vy0 && vx0)) w00 = 0.f;
        if (!(vy0 && vx1)) w01 = 0.f;
        if (!(vy1 && vx0)) w10 = 0.f;
        if (!(vy1 && vx1)) w11 = 0.f;
        int yc0 = min(max(y0, 0), H_ - 1);
        int yc1 = min(max(y0 + 1, 0), H_ - 1);
        int xc0 = min(max(x0, 0), W_ - 1);
        int xc1 = min(max(x0 + 1, 0), W_ - 1);
        Wc[st][0] = (f16x2){(_Float16)w00, (_Float16)w00};
        Wc[st][1] = (f16x2){(_Float16)w01, (_Float16)w01};
        Wc[st][2] = (f16x2){(_Float16)w10, (_Float16)w10};
        Wc[st][3] = (f16x2){(_Float16)w11, (_Float16)w11};
        unsigned long long a00 = (unsigned long long)(xb + ((size_t)((yc0 << 7) + xc0) << 6) + g * 8);
        unsigned long long a01 = (unsigned long long)(xb + ((size_t)((yc0 << 7) + xc1) << 6) + g * 8);
        unsigned long long a10 = (unsigned long long)(xb + ((size_t)((yc1 << 7) + xc0) << 6) + g * 8);
        unsigned long long a11 = (unsigned long long)(xb + ((size_t)((yc1 << 7) + xc1) << 6) + g * 8);
        GLOAD16  (q[st][0], a00); GLOAD16O64(q[st][1], a00);
        GLOAD16  (q[st][2], a01); GLOAD16O64(q[st][3], a01);
        GLOAD16  (q[st][4], a10); GLOAD16O64(q[st][5], a10);
        GLOAD16  (q[st][6], a11); GLOAD16O64(q[st][7], a11);
    };

    pi(0, 0);
#pragma unroll
    for (int kk = 0; kk < KK_; ++kk) {
        const int s = kk & 1, n = s ^ 1;
        if (kk < 8) pi(kk + 1, n);
        if (kk < 8) { WAITV(8); } else { WAITV(0); }
#pragma unroll
        for (int kc = 0; kc < 2; ++kc) {
            f16x8 a;
            f16x2* ap = (f16x2*)&a;
#pragma unroll
            for (int p = 0; p < 4; ++p) {
                ap[p] = u2h(q[s][0 + kc][p]) * Wc[s][0]
                      + u2h(q[s][2 + kc][p]) * Wc[s][1]
                      + u2h(q[s][4 + kc][p]) * Wc[s][2]
                      + u2h(q[s][6 + kc][p]) * Wc[s][3];
            }
#pragma unroll
            for (int nb = 0; nb < 4; ++nb) {
                f16x8 bfr;
                if (kk < 8) {
                    bfr = *(const f16x8*)(wlds +
                        ((((kk * 2 + kc) << 2) + nb) << 9) + (lane << 3));
                } else {
                    bfr = u2h8(wreg[kc * 4 + nb]);
                }
                acc[nb] = __builtin_amdgcn_mfma_f32_16x16x32_f16(a, bfr, acc[nb], 0, 0, 0);
            }
        }
    }

    // C/D: col=lane&15 -> o, row=(lane>>4)*4+r -> px ; 16B vector stores
#pragma unroll
    for (int nb = 0; nb < 4; ++nb) {
        int o = nb * 16 + pr;
        float* outp = out + (((size_t)(b * O_ + o)) << 14) + pxb + (g << 2);
        *(f32x4*)outp = acc[nb];
    }
}

// ===========================================================================
extern "C" void kernel_launch(void* const* d_in, const int* in_sizes, int n_in,
                              void* d_out, int out_size, void* d_ws, size_t ws_size,
                              hipStream_t stream)
{
    const float* x      = (const float*)d_in[0];
    const float* w_off  = (const float*)d_in[1];
    const float* b_off  = (const float*)d_in[2];
    const float* w_conv = (const float*)d_in[3];
    float* out = (float*)d_out;
    char* ws = (char*)d_ws;

    // workspace layout (bytes) — total 21,643,264
    const size_t XT_OFF    = 0;           // 16,777,216  f16 NHWC x
    const size_t OFFS_OFF  = 16777216;    //  4,718,592  f16 NHWC offsets
    const size_t WFRAG_OFF = 21495808;    //     73,728  deform weight frags
    const size_t WOFF_OFF  = 21569536;    //     36,864  offset weight frags

    _Float16* xT    = (_Float16*)(ws + XT_OFF);
    _Float16* offsh = (_Float16*)(ws + OFFS_OFF);
    _Float16* wfrag = (_Float16*)(ws + WFRAG_OFF);
    _Float16* wofff = (_Float16*)(ws + WOFF_OFF);

    transpose_x  <<<2048, 256, 0, stream>>>(x, xT);
    prep3        <<<144, 256, 0, stream>>>(w_conv, w_off, wfrag, wofff);
    offconv_mfma3<<<2048, 256, 0, stream>>>(xT, wofff, b_off, offsh);
    deform_mfma4 <<<2048, 256, 0, stream>>>(xT, offsh, wfrag, out);
}

// Round 7
// 106.042 us; speedup vs baseline: 3.9755x; 1.0110x over previous
//
#include <hip/hip_runtime.h>

#define B_    8
#define C_    64
#define O_    64
#define H_    128
#define W_    128
#define HW_   (H_ * W_)
#define NOFF_ 18
#define KK_   9

typedef __attribute__((ext_vector_type(8))) _Float16 f16x8;
typedef __attribute__((ext_vector_type(2))) _Float16 f16x2;
typedef __attribute__((ext_vector_type(4))) unsigned int u32x4;
typedef __attribute__((ext_vector_type(4))) float f32x4;
typedef unsigned int uint32;
typedef unsigned short ushort;

__device__ __forceinline__ f16x2 u2h(uint32 u) {
    union { uint32 u; f16x2 h; } c; c.u = u; return c.h;
}
__device__ __forceinline__ f16x8 u2h8(u32x4 q) {
    union { u32x4 u; f16x8 h; } c; c.u = q; return c.h;
}

// asm-pinned 16B global loads. "=&v" EARLY-CLOBBER: dest may never alias the
// address pair (async return would corrupt a live address register).
#define GLOAD16(dst, a64) \
    asm volatile("global_load_dwordx4 %0, %1, off" : "=&v"(dst) : "v"(a64) : "memory")
#define GLOAD16O64(dst, a64) \
    asm volatile("global_load_dwordx4 %0, %1, off offset:64" : "=&v"(dst) : "v"(a64) : "memory")
#define WAITV(N) do { \
    asm volatile("s_waitcnt vmcnt(" #N ")" ::: "memory"); \
    __builtin_amdgcn_sched_barrier(0); } while (0)
// Full drain + scheduling fence: guarantees NO compiler VMEM (staging, dpk,
// wreg) is outstanding or can be sunk past this point -> counted vmcnt valid.
#define DRAIN_ALL() do { \
    asm volatile("s_waitcnt vmcnt(0) lgkmcnt(0)" ::: "memory"); \
    __builtin_amdgcn_sched_barrier(0); } while (0)

// ---------------------------------------------------------------------------
// x [b][c][hw] f32  ->  xT [b][hw][c] f16   (LDS tile transpose)
// ---------------------------------------------------------------------------
__global__ __launch_bounds__(256) void transpose_x(
    const float* __restrict__ x, _Float16* __restrict__ xT)
{
    __shared__ float tile[64][65];
    int blk = blockIdx.x;
    int b   = blk >> 8;
    int hw0 = (blk & 255) * 64;
    int t   = threadIdx.x;
    int q   = t >> 6;
    int ln  = t & 63;
#pragma unroll
    for (int p = 0; p < 16; ++p) {
        int c = p * 4 + q;
        tile[c][ln] = x[((size_t)(b * C_ + c) << 14) + hw0 + ln];
    }
    __syncthreads();
#pragma unroll
    for (int p = 0; p < 16; ++p) {
        int hw = p * 4 + q;
        xT[(((size_t)b << 14) + hw0 + hw) * 64 + ln] = (_Float16)tile[ln][hw];
    }
}

// ---------------------------------------------------------------------------
// Weight fragments (f16).
// wfrag[kk][kc][nb4][lane][i] <- w_conv : c=kc*32+(lane>>4)*8+i, o=nb*16+(lane&15)
// wofff[kk][kc][nb2][lane][i] <- w_off  : m=nb*16+(lane&15) (0 for m>=18)
// ---------------------------------------------------------------------------
__global__ __launch_bounds__(256) void prep3(
    const float* __restrict__ w_conv, const float* __restrict__ w_off,
    _Float16* __restrict__ wfrag, _Float16* __restrict__ wofff)
{
    int idx = blockIdx.x * 256 + threadIdx.x;
    if (idx < 36864) {
        int i    = idx & 7;
        int lane = (idx >> 3) & 63;
        int nb   = (idx >> 9) & 3;
        int kc   = (idx >> 11) & 1;
        int kk   = idx >> 12;
        int c = kc * 32 + ((lane >> 4) << 3) + i;
        int o = nb * 16 + (lane & 15);
        wfrag[idx] = (_Float16)w_conv[(o * C_ + c) * 9 + kk];
    }
    if (idx < 18432) {
        int i    = idx & 7;
        int lane = (idx >> 3) & 63;
        int nb   = (idx >> 9) & 1;
        int kc   = (idx >> 10) & 1;
        int kk   = idx >> 11;
        int m = nb * 16 + (lane & 15);
        int c = kc * 32 + ((lane >> 4) << 3) + i;
        wofff[idx] = (_Float16)((m < NOFF_) ? w_off[(m * C_ + c) * 9 + kk] : 0.0f);
    }
}

// ---------------------------------------------------------------------------
// Offset conv as MFMA, weights in 36 KB LDS shared by 8 waves (512 thr).
// Asm-pinned gathers 3-deep (vmcnt(4)). R5-proven loop body.
// ---------------------------------------------------------------------------
__global__ __launch_bounds__(512, 2) void offconv_mfma5(
    const _Float16* __restrict__ xT, const _Float16* __restrict__ wofff,
    const float* __restrict__ b_off, _Float16* __restrict__ offsh)
{
    __shared__ _Float16 wlds[18432];          // 36,864 B: all 9 kk offset-weight frags
    int t = threadIdx.x;
    {
        const u32x4* src = (const u32x4*)wofff;
        u32x4* dst = (u32x4*)wlds;
#pragma unroll
        for (int r = 0; r < 5; ++r) {
            int i = r * 512 + t;
            if (i < 2304) dst[i] = src[i];
        }
    }
    DRAIN_ALL();
    __syncthreads();

    int blk  = blockIdx.x;
    int b    = blk & 7;
    int hw0  = (blk >> 3) * 128;
    int lane = t & 63;
    int wv   = t >> 6;
    int pxb  = hw0 + wv * 16;
    int pr   = lane & 15;
    int g    = lane >> 4;
    int px   = pxb + pr;
    int h = px >> 7, w = px & (W_ - 1);
    const _Float16* xb = xT + (((size_t)b << 14) << 6);

    f32x4 acc[2];
#pragma unroll
    for (int nb = 0; nb < 2; ++nb) acc[nb] = (f32x4){0.f, 0.f, 0.f, 0.f};

    u32x4 q[3][2];
    bool  vld[3];

    auto issueO = [&](int kk, int st) {
        int ky = kk / 3, kx = kk % 3;
        int yy = h - 1 + ky, xx = w - 1 + kx;
        vld[st] = ((unsigned)yy < (unsigned)H_) && ((unsigned)xx < (unsigned)W_);
        int src = (min(max(yy, 0), H_ - 1) << 7) + min(max(xx, 0), W_ - 1);
        unsigned long long a = (unsigned long long)(xb + ((size_t)src << 6) + g * 8);
        GLOAD16(q[st][0], a);
        GLOAD16O64(q[st][1], a);              // channels +32 = +64 B
    };

    issueO(0, 0); issueO(1, 1); issueO(2, 2);
#pragma unroll
    for (int kk = 0; kk < KK_; ++kk) {
        const int s = kk % 3;
        if (kk < 7)      { WAITV(4); }
        else if (kk < 8) { WAITV(2); }
        else             { WAITV(0); }
#pragma unroll
        for (int kc = 0; kc < 2; ++kc) {
            f16x8 a = u2h8(q[s][kc]);
            f16x8 z = {};
            a = vld[s] ? a : z;
#pragma unroll
            for (int nb = 0; nb < 2; ++nb) {
                f16x8 bfr = *(const f16x8*)(wlds +
                    ((((kk * 2 + kc) << 1) + nb) << 9) + (lane << 3));
                acc[nb] = __builtin_amdgcn_mfma_f32_16x16x32_f16(a, bfr, acc[nb], 0, 0, 0);
            }
        }
        if (kk < 6) issueO(kk + 3, s);        // reuse slot s after consumption
    }

    // C/D: col=lane&15 -> m, row=(lane>>4)*4+r -> px
#pragma unroll
    for (int nb = 0; nb < 2; ++nb) {
        int m = nb * 16 + pr;
        if (m < NOFF_) {
            float bias = b_off[m];
#pragma unroll
            for (int r = 0; r < 4; ++r) {
                int prow = pxb + g * 4 + r;
                offsh[(size_t)((b << 14) + prow) * NOFF_ + m] = (_Float16)(acc[nb][r] + bias);
            }
        }
    }
}

// ---------------------------------------------------------------------------
// Deformable conv (R5-proven body at 512 thr): weights kk=0..7 in 64 KB static
// LDS shared by 8 waves -> 2 blocks/CU = 16 waves/CU; kk=8 frags in VGPRs.
// Asm-pinned gathers double-buffered, s_waitcnt vmcnt(8), zero in-loop barriers.
// ---------------------------------------------------------------------------
__global__ __launch_bounds__(512, 2) void deform_mfma6(
    const _Float16* __restrict__ xT, const _Float16* __restrict__ offsh,
    const _Float16* __restrict__ wfrag, float* __restrict__ out)
{
    __shared__ _Float16 wlds[32768];          // 65,536 B: frags (kk*2+kc)*4+nb, kk<8
    int t    = threadIdx.x;
    int blk  = blockIdx.x;
    int b    = blk & 7;                       // XCD-aligned batch
    int hw0  = (blk >> 3) * 128;
    int lane = t & 63;
    int wv   = t >> 6;
    int pxb  = hw0 + wv * 16;
    int pr   = lane & 15;
    int g    = lane >> 4;
    int px   = pxb + pr;
    int h = px >> 7, w = px & (W_ - 1);
    const _Float16* xb = xT + (((size_t)b << 14) << 6);

    // ---- ALL compiler VMEM before the fence+barrier ----
    {
        const u32x4* src = (const u32x4*)wfrag;
        u32x4* dst = (u32x4*)wlds;
#pragma unroll
        for (int r = 0; r < 8; ++r) dst[r * 512 + t] = src[r * 512 + t];
    }
    // kk=8 weight frags -> registers (frag id 64+f, f = kc*4+nb)
    u32x4 wreg[8];
#pragma unroll
    for (int f = 0; f < 8; ++f)
        wreg[f] = *(const u32x4*)(wfrag + ((64 + f) << 9) + (lane << 3));
    // hoist 9 offset pairs
    const uint32* obu = (const uint32*)(offsh + (size_t)((b << 14) + px) * NOFF_);
    uint32 dpk[9];
#pragma unroll
    for (int kk = 0; kk < 9; ++kk) dpk[kk] = obu[kk];
    DRAIN_ALL();                              // vmcnt=0 guaranteed from here
    __syncthreads();

    f32x4 acc[4];
#pragma unroll
    for (int nb = 0; nb < 4; ++nb) acc[nb] = (f32x4){0.f, 0.f, 0.f, 0.f};

    u32x4 q[2][8];                            // [stage][corner*2 + kc]
    f16x2 Wc[2][4];                           // packed corner weights

    auto pi = [&](int kk, int st) {           // prep + issue (asm) for stage st
        union { uint32 u; f16x2 hh; } cv; cv.u = dpk[kk];
        float dyv = (float)cv.hh[0], dxv = (float)cv.hh[1];
        int ky = kk / 3, kx = kk % 3;
        float py  = (float)(h - 1 + ky) + dyv;
        float pxf = (float)(w - 1 + kx) + dxv;
        float y0f = floorf(py), x0f = floorf(pxf);
        float ly = py - y0f, lx = pxf - x0f;
        int y0 = (int)y0f, x0 = (int)x0f;
        float w00 = (1.f - ly) * (1.f - lx);
        float w01 = (1.f - ly) * lx;
        float w10 = ly * (1.f - lx);
        float w11 = ly * lx;
        bool vy0 = (unsigned)y0       < (unsigned)H_;
        bool vy1 = (unsigned)(y0 + 1) < (unsigned)H_;
        bool vx0 = (unsigned)x0       < (unsigned)W_;
        bool vx1 = (unsigned)(x0 + 1) < (unsigned)W_;
        if (!(vy0 && vx0)) w00 = 0.f;
        if (!(vy0 && vx1)) w01 = 0.f;
        if (!(vy1 && vx0)) w10 = 0.f;
        if (!(vy1 && vx1)) w11 = 0.f;
        int yc0 = min(max(y0, 0), H_ - 1);
        int yc1 = min(max(y0 + 1, 0), H_ - 1);
        int xc0 = min(max(x0, 0), W_ - 1);
        int xc1 = min(max(x0 + 1, 0), W_ - 1);
        Wc[st][0] = (f16x2){(_Float16)w00, (_Float16)w00};
        Wc[st][1] = (f16x2){(_Float16)w01, (_Float16)w01};
        Wc[st][2] = (f16x2){(_Float16)w10, (_Float16)w10};
        Wc[st][3] = (f16x2){(_Float16)w11, (_Float16)w11};
        unsigned long long a00 = (unsigned long long)(xb + ((size_t)((yc0 << 7) + xc0) << 6) + g * 8);
        unsigned long long a01 = (unsigned long long)(xb + ((size_t)((yc0 << 7) + xc1) << 6) + g * 8);
        unsigned long long a10 = (unsigned long long)(xb + ((size_t)((yc1 << 7) + xc0) << 6) + g * 8);
        unsigned long long a11 = (unsigned long long)(xb + ((size_t)((yc1 << 7) + xc1) << 6) + g * 8);
        GLOAD16  (q[st][0], a00); GLOAD16O64(q[st][1], a00);
        GLOAD16  (q[st][2], a01); GLOAD16O64(q[st][3], a01);
        GLOAD16  (q[st][4], a10); GLOAD16O64(q[st][5], a10);
        GLOAD16  (q[st][6], a11); GLOAD16O64(q[st][7], a11);
    };

    pi(0, 0);
#pragma unroll
    for (int kk = 0; kk < KK_; ++kk) {
        const int s = kk & 1, n = s ^ 1;
        if (kk < 8) pi(kk + 1, n);
        if (kk < 8) { WAITV(8); } else { WAITV(0); }
#pragma unroll
        for (int kc = 0; kc < 2; ++kc) {
            f16x8 a;
            f16x2* ap = (f16x2*)&a;
#pragma unroll
            for (int p = 0; p < 4; ++p) {
                ap[p] = u2h(q[s][0 + kc][p]) * Wc[s][0]
                      + u2h(q[s][2 + kc][p]) * Wc[s][1]
                      + u2h(q[s][4 + kc][p]) * Wc[s][2]
                      + u2h(q[s][6 + kc][p]) * Wc[s][3];
            }
#pragma unroll
            for (int nb = 0; nb < 4; ++nb) {
                f16x8 bfr;
                if (kk < 8) {
                    bfr = *(const f16x8*)(wlds +
                        ((((kk * 2 + kc) << 2) + nb) << 9) + (lane << 3));
                } else {
                    bfr = u2h8(wreg[kc * 4 + nb]);
                }
                acc[nb] = __builtin_amdgcn_mfma_f32_16x16x32_f16(a, bfr, acc[nb], 0, 0, 0);
            }
        }
    }

    // C/D: col=lane&15 -> o, row=(lane>>4)*4+r -> px ; 16B vector stores
#pragma unroll
    for (int nb = 0; nb < 4; ++nb) {
        int o = nb * 16 + pr;
        float* outp = out + (((size_t)(b * O_ + o)) << 14) + pxb + (g << 2);
        *(f32x4*)outp = acc[nb];
    }
}

// ===========================================================================
extern "C" void kernel_launch(void* const* d_in, const int* in_sizes, int n_in,
                              void* d_out, int out_size, void* d_ws, size_t ws_size,
                              hipStream_t stream)
{
    const float* x      = (const float*)d_in[0];
    const float* w_off  = (const float*)d_in[1];
    const float* b_off  = (const float*)d_in[2];
    const float* w_conv = (const float*)d_in[3];
    float* out = (float*)d_out;
    char* ws = (char*)d_ws;

    // workspace layout (bytes) — total 21,643,264
    const size_t XT_OFF    = 0;           // 16,777,216  f16 NHWC x
    const size_t OFFS_OFF  = 16777216;    //  4,718,592  f16 NHWC offsets
    const size_t WFRAG_OFF = 21495808;    //     73,728  deform weight frags
    const size_t WOFF_OFF  = 21569536;    //     36,864  offset weight frags

    _Float16* xT    = (_Float16*)(ws + XT_OFF);
    _Float16* offsh = (_Float16*)(ws + OFFS_OFF);
    _Float16* wfrag = (_Float16*)(ws + WFRAG_OFF);
    _Float16* wofff = (_Float16*)(ws + WOFF_OFF);

    transpose_x  <<<2048, 256, 0, stream>>>(x, xT);
    prep3        <<<144, 256, 0, stream>>>(w_conv, w_off, wfrag, wofff);
    offconv_mfma5<<<1024, 512, 0, stream>>>(xT, wofff, b_off, offsh);
    deform_mfma6 <<<1024, 512, 0, stream>>>(xT, offsh, wfrag, out);
}

// Round 8
// 72.113 us; speedup vs baseline: 5.8459x; 1.4705x over previous
//
#include <hip/hip_runtime.h>

#define B_    8
#define C_    64
#define O_    64
#define H_    128
#define W_    128
#define HW_   (H_ * W_)
#define NOFF_ 18
#define KK_   9

typedef __attribute__((ext_vector_type(8))) _Float16 f16x8;
typedef __attribute__((ext_vector_type(2))) _Float16 f16x2;
typedef __attribute__((ext_vector_type(4))) unsigned int u32x4;
typedef __attribute__((ext_vector_type(4))) float f32x4;
typedef unsigned int uint32;
typedef unsigned short ushort;

__device__ __forceinline__ f16x2 u2h(uint32 u) {
    union { uint32 u; f16x2 h; } c; c.u = u; return c.h;
}
__device__ __forceinline__ f16x8 u2h8(u32x4 q) {
    union { u32x4 u; f16x8 h; } c; c.u = q; return c.h;
}

// asm-pinned 16B global loads. "=&v" early-clobber (R6 lesson).
#define GLOAD16(dst, a64) \
    asm volatile("global_load_dwordx4 %0, %1, off" : "=&v"(dst) : "v"(a64) : "memory")
#define GLOAD16O64(dst, a64) \
    asm volatile("global_load_dwordx4 %0, %1, off offset:64" : "=&v"(dst) : "v"(a64) : "memory")
#define WAITV(N) do { \
    asm volatile("s_waitcnt vmcnt(" #N ")" ::: "memory"); \
    __builtin_amdgcn_sched_barrier(0); } while (0)
#define WAITLGKM0() do { \
    asm volatile("s_waitcnt lgkmcnt(0)" ::: "memory"); \
    __builtin_amdgcn_sched_barrier(0); } while (0)
#define DRAIN_ALL() do { \
    asm volatile("s_waitcnt vmcnt(0) lgkmcnt(0)" ::: "memory"); \
    __builtin_amdgcn_sched_barrier(0); } while (0)

// ---------------------------------------------------------------------------
// x [b][c][hw] f32  ->  xT [b][hw][c] f16   (LDS tile transpose)
// ---------------------------------------------------------------------------
__global__ __launch_bounds__(256) void transpose_x(
    const float* __restrict__ x, _Float16* __restrict__ xT)
{
    __shared__ float tile[64][65];
    int blk = blockIdx.x;
    int b   = blk >> 8;
    int hw0 = (blk & 255) * 64;
    int t   = threadIdx.x;
    int q   = t >> 6;
    int ln  = t & 63;
#pragma unroll
    for (int p = 0; p < 16; ++p) {
        int c = p * 4 + q;
        tile[c][ln] = x[((size_t)(b * C_ + c) << 14) + hw0 + ln];
    }
    __syncthreads();
#pragma unroll
    for (int p = 0; p < 16; ++p) {
        int hw = p * 4 + q;
        xT[(((size_t)b << 14) + hw0 + hw) * 64 + ln] = (_Float16)tile[ln][hw];
    }
}

// ---------------------------------------------------------------------------
// Weight fragments (f16).
// ---------------------------------------------------------------------------
__global__ __launch_bounds__(256) void prep3(
    const float* __restrict__ w_conv, const float* __restrict__ w_off,
    _Float16* __restrict__ wfrag, _Float16* __restrict__ wofff)
{
    int idx = blockIdx.x * 256 + threadIdx.x;
    if (idx < 36864) {
        int i    = idx & 7;
        int lane = (idx >> 3) & 63;
        int nb   = (idx >> 9) & 3;
        int kc   = (idx >> 11) & 1;
        int kk   = idx >> 12;
        int c = kc * 32 + ((lane >> 4) << 3) + i;
        int o = nb * 16 + (lane & 15);
        wfrag[idx] = (_Float16)w_conv[(o * C_ + c) * 9 + kk];
    }
    if (idx < 18432) {
        int i    = idx & 7;
        int lane = (idx >> 3) & 63;
        int nb   = (idx >> 9) & 1;
        int kc   = (idx >> 10) & 1;
        int kk   = idx >> 11;
        int m = nb * 16 + (lane & 15);
        int c = kc * 32 + ((lane >> 4) << 3) + i;
        wofff[idx] = (_Float16)((m < NOFF_) ? w_off[(m * C_ + c) * 9 + kk] : 0.0f);
    }
}

// ---------------------------------------------------------------------------
// Offset conv (R7-proven, unchanged).
// ---------------------------------------------------------------------------
__global__ __launch_bounds__(512, 2) void offconv_mfma5(
    const _Float16* __restrict__ xT, const _Float16* __restrict__ wofff,
    const float* __restrict__ b_off, _Float16* __restrict__ offsh)
{
    __shared__ _Float16 wlds[18432];
    int t = threadIdx.x;
    {
        const u32x4* src = (const u32x4*)wofff;
        u32x4* dst = (u32x4*)wlds;
#pragma unroll
        for (int r = 0; r < 5; ++r) {
            int i = r * 512 + t;
            if (i < 2304) dst[i] = src[i];
        }
    }
    DRAIN_ALL();
    __syncthreads();

    int blk  = blockIdx.x;
    int b    = blk & 7;
    int hw0  = (blk >> 3) * 128;
    int lane = t & 63;
    int wv   = t >> 6;
    int pxb  = hw0 + wv * 16;
    int pr   = lane & 15;
    int g    = lane >> 4;
    int px   = pxb + pr;
    int h = px >> 7, w = px & (W_ - 1);
    const _Float16* xb = xT + (((size_t)b << 14) << 6);

    f32x4 acc[2];
#pragma unroll
    for (int nb = 0; nb < 2; ++nb) acc[nb] = (f32x4){0.f, 0.f, 0.f, 0.f};

    u32x4 q[3][2];
    bool  vld[3];

    auto issueO = [&](int kk, int st) {
        int ky = kk / 3, kx = kk % 3;
        int yy = h - 1 + ky, xx = w - 1 + kx;
        vld[st] = ((unsigned)yy < (unsigned)H_) && ((unsigned)xx < (unsigned)W_);
        int src = (min(max(yy, 0), H_ - 1) << 7) + min(max(xx, 0), W_ - 1);
        unsigned long long a = (unsigned long long)(xb + ((size_t)src << 6) + g * 8);
        GLOAD16(q[st][0], a);
        GLOAD16O64(q[st][1], a);
    };

    issueO(0, 0); issueO(1, 1); issueO(2, 2);
#pragma unroll
    for (int kk = 0; kk < KK_; ++kk) {
        const int s = kk % 3;
        if (kk < 7)      { WAITV(4); }
        else if (kk < 8) { WAITV(2); }
        else             { WAITV(0); }
#pragma unroll
        for (int kc = 0; kc < 2; ++kc) {
            f16x8 a = u2h8(q[s][kc]);
            f16x8 z = {};
            a = vld[s] ? a : z;
#pragma unroll
            for (int nb = 0; nb < 2; ++nb) {
                f16x8 bfr = *(const f16x8*)(wlds +
                    ((((kk * 2 + kc) << 1) + nb) << 9) + (lane << 3));
                acc[nb] = __builtin_amdgcn_mfma_f32_16x16x32_f16(a, bfr, acc[nb], 0, 0, 0);
            }
        }
        if (kk < 6) issueO(kk + 3, s);
    }

#pragma unroll
    for (int nb = 0; nb < 2; ++nb) {
        int m = nb * 16 + pr;
        if (m < NOFF_) {
            float bias = b_off[m];
#pragma unroll
            for (int r = 0; r < 4; ++r) {
                int prow = pxb + g * 4 + r;
                offsh[(size_t)((b << 14) + prow) * NOFF_ + m] = (_Float16)(acc[nb][r] + bias);
            }
        }
    }
}

// ---------------------------------------------------------------------------
// Deformable conv R8: COALESCED corner gathers. Per instruction, 8 lanes x 16B
// cover ONE pixel's full 128B NHWC line (8 px per instr); bilerp in-lane;
// 2 KB wave-private swizzled LDS bounce converts to MFMA A-fragment layout.
// Weights kk<8 in LDS, kk=8 in regs; asm double-buffer, vmcnt(8).
// ---------------------------------------------------------------------------
__global__ __launch_bounds__(256, 2) void deform_mfma7(
    const _Float16* __restrict__ xT, const _Float16* __restrict__ offsh,
    const _Float16* __restrict__ wfrag, float* __restrict__ out)
{
    __shared__ _Float16 wlds[32768];          // 65,536 B weights kk=0..7
    __shared__ _Float16 val[4][1024];         // 2 KB per wave, swizzled [px][ch]

    int t    = threadIdx.x;
    int blk  = blockIdx.x;
    int b    = blk & 7;                       // XCD-aligned batch
    int hw0  = (blk >> 3) * 64;
    int lane = t & 63;
    int wv   = t >> 6;
    int pxb  = hw0 + wv * 16;
    int pr   = lane & 15;                     // fragment role: pixel row
    int gg   = lane >> 4;                     // fragment role: k-group
    int gp   = lane >> 3;                     // gather role: pixel-in-half 0..7
    int cg   = lane & 7;                      // gather role: 16B chunk 0..7
    const _Float16* xb = xT + (((size_t)b << 14) << 6);

    // ---- ALL compiler VMEM before the fence+barrier ----
    {
        const u32x4* src = (const u32x4*)wfrag;
        u32x4* dst = (u32x4*)wlds;
#pragma unroll
        for (int r = 0; r < 16; ++r) dst[r * 256 + t] = src[r * 256 + t];
    }
    u32x4 wreg[8];                            // kk=8 frags
#pragma unroll
    for (int f = 0; f < 8; ++f)
        wreg[f] = *(const u32x4*)(wfrag + ((64 + f) << 9) + (lane << 3));
    const uint32* obu = (const uint32*)(offsh + (size_t)((b << 14) + pxb + pr) * NOFF_);
    uint32 dpk[9];
#pragma unroll
    for (int kk = 0; kk < 9; ++kk) dpk[kk] = obu[kk];
    DRAIN_ALL();
    __syncthreads();

    f32x4 acc[4];
#pragma unroll
    for (int nb = 0; nb < 4; ++nb) acc[nb] = (f32x4){0.f, 0.f, 0.f, 0.f};

    u32x4 q[2][8];                            // [stage][h*4 + corner]
    f16x2 Wc[2][2][4];                        // [stage][h][corner]

    auto pi = [&](int kk, int st) {
        int ky = kk / 3, kx = kk % 3;
#pragma unroll
        for (int h2 = 0; h2 < 2; ++h2) {
            int p = pxb + h2 * 8 + gp;        // pixel this lane loads for
            uint32 du = __shfl(dpk[kk], h2 * 8 + gp, 64);
            union { uint32 u; f16x2 hh; } cv; cv.u = du;
            float dyv = (float)cv.hh[0], dxv = (float)cv.hh[1];
            int hp = p >> 7, wp = p & (W_ - 1);
            float py  = (float)(hp - 1 + ky) + dyv;
            float pxf = (float)(wp - 1 + kx) + dxv;
            float y0f = floorf(py), x0f = floorf(pxf);
            float ly = py - y0f, lx = pxf - x0f;
            int y0 = (int)y0f, x0 = (int)x0f;
            float w00 = (1.f - ly) * (1.f - lx);
            float w01 = (1.f - ly) * lx;
            float w10 = ly * (1.f - lx);
            float w11 = ly * lx;
            bool vy0 = (unsigned)y0       < (unsigned)H_;
            bool vy1 = (unsigned)(y0 + 1) < (unsigned)H_;
            bool vx0 = (unsigned)x0       < (unsigned)W_;
            bool vx1 = (unsigned)(x0 + 1) < (unsigned)W_;
            if (!(vy0 && vx0)) w00 = 0.f;
            if (!(vy0 && vx1)) w01 = 0.f;
            if (!(vy1 && vx0)) w10 = 0.f;
            if (!(vy1 && vx1)) w11 = 0.f;
            int yc0 = min(max(y0, 0), H_ - 1);
            int yc1 = min(max(y0 + 1, 0), H_ - 1);
            int xc0 = min(max(x0, 0), W_ - 1);
            int xc1 = min(max(x0 + 1, 0), W_ - 1);
            Wc[st][h2][0] = (f16x2){(_Float16)w00, (_Float16)w00};
            Wc[st][h2][1] = (f16x2){(_Float16)w01, (_Float16)w01};
            Wc[st][h2][2] = (f16x2){(_Float16)w10, (_Float16)w10};
            Wc[st][h2][3] = (f16x2){(_Float16)w11, (_Float16)w11};
            unsigned long long base = (unsigned long long)xb + ((unsigned long long)cg << 4);
            uint32 o00 = ((uint32)((yc0 << 7) + xc0)) << 7;
            uint32 o01 = ((uint32)((yc0 << 7) + xc1)) << 7;
            uint32 o10 = ((uint32)((yc1 << 7) + xc0)) << 7;
            uint32 o11 = ((uint32)((yc1 << 7) + xc1)) << 7;
            GLOAD16(q[st][h2 * 4 + 0], base + o00);   // 8 lanes/px: full 128B line
            GLOAD16(q[st][h2 * 4 + 1], base + o01);
            GLOAD16(q[st][h2 * 4 + 2], base + o10);
            GLOAD16(q[st][h2 * 4 + 3], base + o11);
        }
    };

    char* mv = (char*)val[wv];                // wave-private 2KB slot

    pi(0, 0);
#pragma unroll
    for (int kk = 0; kk < KK_; ++kk) {
        const int s = kk & 1, n = s ^ 1;
        if (kk < 8) pi(kk + 1, n);
        if (kk < 8) { WAITV(8); } else { WAITV(0); }

        // bilerp both pixel-halves in-lane, write swizzled to val
#pragma unroll
        for (int h2 = 0; h2 < 2; ++h2) {
            f16x8 r;
            f16x2* rp = (f16x2*)&r;
#pragma unroll
            for (int p4 = 0; p4 < 4; ++p4) {
                rp[p4] = u2h(q[s][h2 * 4 + 0][p4]) * Wc[s][h2][0]
                       + u2h(q[s][h2 * 4 + 1][p4]) * Wc[s][h2][1]
                       + u2h(q[s][h2 * 4 + 2][p4]) * Wc[s][h2][2]
                       + u2h(q[s][h2 * 4 + 3][p4]) * Wc[s][h2][3];
            }
            int pxw = h2 * 8 + gp;
            int wb  = (pxw << 7) + (cg << 4);
            *(f16x8*)(mv + (wb ^ ((pxw & 7) << 4))) = r;
        }
        WAITLGKM0();                          // write->read, same wave, no barrier

        // read A-fragments (swizzled): lane pr+16gg <- px pr, ch kc*32+gg*8
        f16x8 a0 = *(const f16x8*)(mv + (((pr << 7) + (gg << 4))      ^ ((pr & 7) << 4)));
        f16x8 a1 = *(const f16x8*)(mv + (((pr << 7) + 64 + (gg << 4)) ^ ((pr & 7) << 4)));

#pragma unroll
        for (int kc = 0; kc < 2; ++kc) {
            f16x8 a = kc ? a1 : a0;
#pragma unroll
            for (int nb = 0; nb < 4; ++nb) {
                f16x8 bfr;
                if (kk < 8) {
                    bfr = *(const f16x8*)(wlds +
                        ((((kk * 2 + kc) << 2) + nb) << 9) + (lane << 3));
                } else {
                    bfr = u2h8(wreg[kc * 4 + nb]);
                }
                acc[nb] = __builtin_amdgcn_mfma_f32_16x16x32_f16(a, bfr, acc[nb], 0, 0, 0);
            }
        }
    }

    // C/D: col=lane&15 -> o, row=(lane>>4)*4+r -> px ; 16B vector stores
#pragma unroll
    for (int nb = 0; nb < 4; ++nb) {
        int o = nb * 16 + pr;
        float* outp = out + (((size_t)(b * O_ + o)) << 14) + pxb + (gg << 2);
        *(f32x4*)outp = acc[nb];
    }
}

// ===========================================================================
extern "C" void kernel_launch(void* const* d_in, const int* in_sizes, int n_in,
                              void* d_out, int out_size, void* d_ws, size_t ws_size,
                              hipStream_t stream)
{
    const float* x      = (const float*)d_in[0];
    const float* w_off  = (const float*)d_in[1];
    const float* b_off  = (const float*)d_in[2];
    const float* w_conv = (const float*)d_in[3];
    float* out = (float*)d_out;
    char* ws = (char*)d_ws;

    // workspace layout (bytes) — total 21,643,264
    const size_t XT_OFF    = 0;           // 16,777,216  f16 NHWC x
    const size_t OFFS_OFF  = 16777216;    //  4,718,592  f16 NHWC offsets
    const size_t WFRAG_OFF = 21495808;    //     73,728  deform weight frags
    const size_t WOFF_OFF  = 21569536;    //     36,864  offset weight frags

    _Float16* xT    = (_Float16*)(ws + XT_OFF);
    _Float16* offsh = (_Float16*)(ws + OFFS_OFF);
    _Float16* wfrag = (_Float16*)(ws + WFRAG_OFF);
    _Float16* wofff = (_Float16*)(ws + WOFF_OFF);

    transpose_x  <<<2048, 256, 0, stream>>>(x, xT);
    prep3        <<<144, 256, 0, stream>>>(w_conv, w_off, wfrag, wofff);
    offconv_mfma5<<<1024, 512, 0, stream>>>(xT, wofff, b_off, offsh);
    deform_mfma7 <<<2048, 256, 0, stream>>>(xT, offsh, wfrag, out);
}

// Round 9
// 70.762 us; speedup vs baseline: 5.9575x; 1.0191x over previous
//
#include <hip/hip_runtime.h>

#define B_    8
#define C_    64
#define O_    64
#define H_    128
#define W_    128
#define HW_   (H_ * W_)
#define NOFF_ 18
#define KK_   9

typedef __attribute__((ext_vector_type(8))) _Float16 f16x8;
typedef __attribute__((ext_vector_type(2))) _Float16 f16x2;
typedef __attribute__((ext_vector_type(4))) unsigned int u32x4;
typedef __attribute__((ext_vector_type(4))) float f32x4;
typedef unsigned int uint32;
typedef unsigned short ushort;

__device__ __forceinline__ f16x2 u2h(uint32 u) {
    union { uint32 u; f16x2 h; } c; c.u = u; return c.h;
}
__device__ __forceinline__ f16x8 u2h8(u32x4 q) {
    union { u32x4 u; f16x8 h; } c; c.u = q; return c.h;
}

// asm-pinned 16B global loads. "=&v" early-clobber (R6 lesson).
#define GLOAD16(dst, a64) \
    asm volatile("global_load_dwordx4 %0, %1, off" : "=&v"(dst) : "v"(a64) : "memory")
#define WAITV(N) do { \
    asm volatile("s_waitcnt vmcnt(" #N ")" ::: "memory"); \
    __builtin_amdgcn_sched_barrier(0); } while (0)
#define WAITLGKM0() do { \
    asm volatile("s_waitcnt lgkmcnt(0)" ::: "memory"); \
    __builtin_amdgcn_sched_barrier(0); } while (0)
#define DRAIN_ALL() do { \
    asm volatile("s_waitcnt vmcnt(0) lgkmcnt(0)" ::: "memory"); \
    __builtin_amdgcn_sched_barrier(0); } while (0)

// ---------------------------------------------------------------------------
// x [b][c][hw] f32  ->  xT [b][hw][c] f16   (LDS tile transpose)
// ---------------------------------------------------------------------------
__global__ __launch_bounds__(256) void transpose_x(
    const float* __restrict__ x, _Float16* __restrict__ xT)
{
    __shared__ float tile[64][65];
    int blk = blockIdx.x;
    int b   = blk >> 8;
    int hw0 = (blk & 255) * 64;
    int t   = threadIdx.x;
    int q   = t >> 6;
    int ln  = t & 63;
#pragma unroll
    for (int p = 0; p < 16; ++p) {
        int c = p * 4 + q;
        tile[c][ln] = x[((size_t)(b * C_ + c) << 14) + hw0 + ln];
    }
    __syncthreads();
#pragma unroll
    for (int p = 0; p < 16; ++p) {
        int hw = p * 4 + q;
        xT[(((size_t)b << 14) + hw0 + hw) * 64 + ln] = (_Float16)tile[ln][hw];
    }
}

// ---------------------------------------------------------------------------
// Weight fragments (f16).
// ---------------------------------------------------------------------------
__global__ __launch_bounds__(256) void prep3(
    const float* __restrict__ w_conv, const float* __restrict__ w_off,
    _Float16* __restrict__ wfrag, _Float16* __restrict__ wofff)
{
    int idx = blockIdx.x * 256 + threadIdx.x;
    if (idx < 36864) {
        int i    = idx & 7;
        int lane = (idx >> 3) & 63;
        int nb   = (idx >> 9) & 3;
        int kc   = (idx >> 11) & 1;
        int kk   = idx >> 12;
        int c = kc * 32 + ((lane >> 4) << 3) + i;
        int o = nb * 16 + (lane & 15);
        wfrag[idx] = (_Float16)w_conv[(o * C_ + c) * 9 + kk];
    }
    if (idx < 18432) {
        int i    = idx & 7;
        int lane = (idx >> 3) & 63;
        int nb   = (idx >> 9) & 1;
        int kc   = (idx >> 10) & 1;
        int kk   = idx >> 11;
        int m = nb * 16 + (lane & 15);
        int c = kc * 32 + ((lane >> 4) << 3) + i;
        wofff[idx] = (_Float16)((m < NOFF_) ? w_off[(m * C_ + c) * 9 + kk] : 0.0f);
    }
}

// ---------------------------------------------------------------------------
// Offset conv (R7-proven, unchanged).
// ---------------------------------------------------------------------------
__global__ __launch_bounds__(512, 2) void offconv_mfma5(
    const _Float16* __restrict__ xT, const _Float16* __restrict__ wofff,
    const float* __restrict__ b_off, _Float16* __restrict__ offsh)
{
    __shared__ _Float16 wlds[18432];
    int t = threadIdx.x;
    {
        const u32x4* src = (const u32x4*)wofff;
        u32x4* dst = (u32x4*)wlds;
#pragma unroll
        for (int r = 0; r < 5; ++r) {
            int i = r * 512 + t;
            if (i < 2304) dst[i] = src[i];
        }
    }
    DRAIN_ALL();
    __syncthreads();

    int blk  = blockIdx.x;
    int b    = blk & 7;
    int hw0  = (blk >> 3) * 128;
    int lane = t & 63;
    int wv   = t >> 6;
    int pxb  = hw0 + wv * 16;
    int pr   = lane & 15;
    int g    = lane >> 4;
    int px   = pxb + pr;
    int h = px >> 7, w = px & (W_ - 1);
    const _Float16* xb = xT + (((size_t)b << 14) << 6);

    f32x4 acc[2];
#pragma unroll
    for (int nb = 0; nb < 2; ++nb) acc[nb] = (f32x4){0.f, 0.f, 0.f, 0.f};

    u32x4 q[3][2];
    bool  vld[3];

    auto issueO = [&](int kk, int st) {
        int ky = kk / 3, kx = kk % 3;
        int yy = h - 1 + ky, xx = w - 1 + kx;
        vld[st] = ((unsigned)yy < (unsigned)H_) && ((unsigned)xx < (unsigned)W_);
        int src = (min(max(yy, 0), H_ - 1) << 7) + min(max(xx, 0), W_ - 1);
        unsigned long long a = (unsigned long long)(xb + ((size_t)src << 6) + g * 8);
        GLOAD16(q[st][0], a);
        unsigned long long a2 = a + 64;
        GLOAD16(q[st][1], a2);
    };

    issueO(0, 0); issueO(1, 1); issueO(2, 2);
#pragma unroll
    for (int kk = 0; kk < KK_; ++kk) {
        const int s = kk % 3;
        if (kk < 7)      { WAITV(4); }
        else if (kk < 8) { WAITV(2); }
        else             { WAITV(0); }
#pragma unroll
        for (int kc = 0; kc < 2; ++kc) {
            f16x8 a = u2h8(q[s][kc]);
            f16x8 z = {};
            a = vld[s] ? a : z;
#pragma unroll
            for (int nb = 0; nb < 2; ++nb) {
                f16x8 bfr = *(const f16x8*)(wlds +
                    ((((kk * 2 + kc) << 1) + nb) << 9) + (lane << 3));
                acc[nb] = __builtin_amdgcn_mfma_f32_16x16x32_f16(a, bfr, acc[nb], 0, 0, 0);
            }
        }
        if (kk < 6) issueO(kk + 3, s);
    }

#pragma unroll
    for (int nb = 0; nb < 2; ++nb) {
        int m = nb * 16 + pr;
        if (m < NOFF_) {
            float bias = b_off[m];
#pragma unroll
            for (int r = 0; r < 4; ++r) {
                int prow = pxb + g * 4 + r;
                offsh[(size_t)((b << 14) + prow) * NOFF_ + m] = (_Float16)(acc[nb][r] + bias);
            }
        }
    }
}

// ---------------------------------------------------------------------------
// Deformable conv R9: R8 structure, but weight LDS shrunk to kk=0..4 (40 KB;
// block LDS 48 KB -> 3 blocks/CU = 12 waves) and kk=5..8 weights STREAMED via
// the counted asm pipeline (drops 8 ds_read_b128/kk for those kks, relieving
// the LDS pipe). vmcnt: per iter queue = [w(kk) x8, g(kk+1) x8] -> WAITV(8).
// ---------------------------------------------------------------------------
__global__ __launch_bounds__(256, 3) void deform_mfma8(
    const _Float16* __restrict__ xT, const _Float16* __restrict__ offsh,
    const _Float16* __restrict__ wfrag, float* __restrict__ out)
{
    __shared__ _Float16 wlds[20480];          // 40,960 B: frags kk=0..4
    __shared__ _Float16 val[4][1024];         // 8 KB, wave-private swizzled bounce

    int t    = threadIdx.x;
    int blk  = blockIdx.x;
    int b    = blk & 7;                       // XCD-aligned batch
    int hw0  = (blk >> 3) * 64;
    int lane = t & 63;
    int wv   = t >> 6;
    int pxb  = hw0 + wv * 16;
    int pr   = lane & 15;                     // fragment role: pixel row
    int gg   = lane >> 4;                     // fragment role: k-group
    int gp   = lane >> 3;                     // gather role: pixel-in-half 0..7
    int cg   = lane & 7;                      // gather role: 16B chunk 0..7
    const _Float16* xb = xT + (((size_t)b << 14) << 6);

    // ---- ALL compiler VMEM before the fence+barrier ----
    {
        const u32x4* src = (const u32x4*)wfrag;
        u32x4* dst = (u32x4*)wlds;
#pragma unroll
        for (int r = 0; r < 10; ++r) dst[r * 256 + t] = src[r * 256 + t];
    }
    const uint32* obu = (const uint32*)(offsh + (size_t)((b << 14) + pxb + pr) * NOFF_);
    uint32 dpk[9];
#pragma unroll
    for (int kk = 0; kk < 9; ++kk) dpk[kk] = obu[kk];
    DRAIN_ALL();
    __syncthreads();

    f32x4 acc[4];
#pragma unroll
    for (int nb = 0; nb < 4; ++nb) acc[nb] = (f32x4){0.f, 0.f, 0.f, 0.f};

    u32x4 q[2][8];                            // [stage][h*4 + corner]
    u32x4 wq[8];                              // streamed weight frags (kk>=5)
    f16x2 Wc[2][2][4];                        // [stage][h][corner]

    auto pi = [&](int kk, int st) {
        int ky = kk / 3, kx = kk % 3;
#pragma unroll
        for (int h2 = 0; h2 < 2; ++h2) {
            int p = pxb + h2 * 8 + gp;        // pixel this lane loads for
            uint32 du = __shfl(dpk[kk], h2 * 8 + gp, 64);
            union { uint32 u; f16x2 hh; } cv; cv.u = du;
            float dyv = (float)cv.hh[0], dxv = (float)cv.hh[1];
            int hp = p >> 7, wp = p & (W_ - 1);
            float py  = (float)(hp - 1 + ky) + dyv;
            float pxf = (float)(wp - 1 + kx) + dxv;
            float y0f = floorf(py), x0f = floorf(pxf);
            float ly = py - y0f, lx = pxf - x0f;
            int y0 = (int)y0f, x0 = (int)x0f;
            float w00 = (1.f - ly) * (1.f - lx);
            float w01 = (1.f - ly) * lx;
            float w10 = ly * (1.f - lx);
            float w11 = ly * lx;
            bool vy0 = (unsigned)y0       < (unsigned)H_;
            bool vy1 = (unsigned)(y0 + 1) < (unsigned)H_;
            bool vx0 = (unsigned)x0       < (unsigned)W_;
            bool vx1 = (unsigned)(x0 + 1) < (unsigned)W_;
            if (!(vy0 && vx0)) w00 = 0.f;
            if (!(vy0 && vx1)) w01 = 0.f;
            if (!(vy1 && vx0)) w10 = 0.f;
            if (!(vy1 && vx1)) w11 = 0.f;
            int yc0 = min(max(y0, 0), H_ - 1);
            int yc1 = min(max(y0 + 1, 0), H_ - 1);
            int xc0 = min(max(x0, 0), W_ - 1);
            int xc1 = min(max(x0 + 1, 0), W_ - 1);
            Wc[st][h2][0] = (f16x2){(_Float16)w00, (_Float16)w00};
            Wc[st][h2][1] = (f16x2){(_Float16)w01, (_Float16)w01};
            Wc[st][h2][2] = (f16x2){(_Float16)w10, (_Float16)w10};
            Wc[st][h2][3] = (f16x2){(_Float16)w11, (_Float16)w11};
            unsigned long long base = (unsigned long long)xb + ((unsigned long long)cg << 4);
            uint32 o00 = ((uint32)((yc0 << 7) + xc0)) << 7;
            uint32 o01 = ((uint32)((yc0 << 7) + xc1)) << 7;
            uint32 o10 = ((uint32)((yc1 << 7) + xc0)) << 7;
            uint32 o11 = ((uint32)((yc1 << 7) + xc1)) << 7;
            GLOAD16(q[st][h2 * 4 + 0], base + o00);   // 8 lanes/px: full 128B line
            GLOAD16(q[st][h2 * 4 + 1], base + o01);
            GLOAD16(q[st][h2 * 4 + 2], base + o10);
            GLOAD16(q[st][h2 * 4 + 3], base + o11);
        }
    };

    char* mv = (char*)val[wv];                // wave-private 2KB slot

    pi(0, 0);
#pragma unroll
    for (int kk = 0; kk < KK_; ++kk) {
        const int s = kk & 1, n = s ^ 1;

        // stream this kk's weights (kk>=5) BEFORE next gathers: older in queue
        if (kk >= 5) {
#pragma unroll
            for (int f = 0; f < 8; ++f) {     // f = kc*4 + nb
                int kc = f >> 2, nb = f & 3;
                unsigned long long wa = (unsigned long long)(wfrag +
                    ((((kk * 2 + kc) << 2) + nb) << 9) + (lane << 3));
                GLOAD16(wq[f], wa);
            }
        }
        if (kk < 8) pi(kk + 1, n);
        if (kk < 8) { WAITV(8); } else { WAITV(0); }

        // bilerp both pixel-halves in-lane, write swizzled to val
#pragma unroll
        for (int h2 = 0; h2 < 2; ++h2) {
            f16x8 r;
            f16x2* rp = (f16x2*)&r;
#pragma unroll
            for (int p4 = 0; p4 < 4; ++p4) {
                rp[p4] = u2h(q[s][h2 * 4 + 0][p4]) * Wc[s][h2][0]
                       + u2h(q[s][h2 * 4 + 1][p4]) * Wc[s][h2][1]
                       + u2h(q[s][h2 * 4 + 2][p4]) * Wc[s][h2][2]
                       + u2h(q[s][h2 * 4 + 3][p4]) * Wc[s][h2][3];
            }
            int pxw = h2 * 8 + gp;
            int wb  = (pxw << 7) + (cg << 4);
            *(f16x8*)(mv + (wb ^ ((pxw & 7) << 4))) = r;
        }
        WAITLGKM0();                          // write->read, same wave, no barrier

        // read A-fragments (swizzled): lane pr+16gg <- px pr, ch kc*32+gg*8
        f16x8 a0 = *(const f16x8*)(mv + (((pr << 7) + (gg << 4))      ^ ((pr & 7) << 4)));
        f16x8 a1 = *(const f16x8*)(mv + (((pr << 7) + 64 + (gg << 4)) ^ ((pr & 7) << 4)));

#pragma unroll
        for (int kc = 0; kc < 2; ++kc) {
            f16x8 a = kc ? a1 : a0;
#pragma unroll
            for (int nb = 0; nb < 4; ++nb) {
                f16x8 bfr;
                if (kk < 5) {
                    bfr = *(const f16x8*)(wlds +
                        ((((kk * 2 + kc) << 2) + nb) << 9) + (lane << 3));
                } else {
                    bfr = u2h8(wq[kc * 4 + nb]);
                }
                acc[nb] = __builtin_amdgcn_mfma_f32_16x16x32_f16(a, bfr, acc[nb], 0, 0, 0);
            }
        }
    }

    // C/D: col=lane&15 -> o, row=(lane>>4)*4+r -> px ; 16B vector stores
#pragma unroll
    for (int nb = 0; nb < 4; ++nb) {
        int o = nb * 16 + pr;
        float* outp = out + (((size_t)(b * O_ + o)) << 14) + pxb + (gg << 2);
        *(f32x4*)outp = acc[nb];
    }
}

// ===========================================================================
extern "C" void kernel_launch(void* const* d_in, const int* in_sizes, int n_in,
                              void* d_out, int out_size, void* d_ws, size_t ws_size,
                              hipStream_t stream)
{
    const float* x      = (const float*)d_in[0];
    const float* w_off  = (const float*)d_in[1];
    const float* b_off  = (const float*)d_in[2];
    const float* w_conv = (const float*)d_in[3];
    float* out = (float*)d_out;
    char* ws = (char*)d_ws;

    // workspace layout (bytes) — total 21,643,264
    const size_t XT_OFF    = 0;           // 16,777,216  f16 NHWC x
    const size_t OFFS_OFF  = 16777216;    //  4,718,592  f16 NHWC offsets
    const size_t WFRAG_OFF = 21495808;    //     73,728  deform weight frags
    const size_t WOFF_OFF  = 21569536;    //     36,864  offset weight frags

    _Float16* xT    = (_Float16*)(ws + XT_OFF);
    _Float16* offsh = (_Float16*)(ws + OFFS_OFF);
    _Float16* wfrag = (_Float16*)(ws + WFRAG_OFF);
    _Float16* wofff = (_Float16*)(ws + WOFF_OFF);

    transpose_x  <<<2048, 256, 0, stream>>>(x, xT);
    prep3        <<<144, 256, 0, stream>>>(w_conv, w_off, wfrag, wofff);
    offconv_mfma5<<<1024, 512, 0, stream>>>(xT, wofff, b_off, offsh);
    deform_mfma8 <<<2048, 256, 0, stream>>>(xT, offsh, wfrag, out);
}

// Round 10
// 66.830 us; speedup vs baseline: 6.3080x; 1.0588x over previous
//
#include <hip/hip_runtime.h>

#define B_    8
#define C_    64
#define O_    64
#define H_    128
#define W_    128
#define HW_   (H_ * W_)
#define NOFF_ 18
#define KK_   9
#define TW_   19      // staged tile span (8 + 2*5 + 1)
#define PADW_ 5

typedef __attribute__((ext_vector_type(8))) _Float16 f16x8;
typedef __attribute__((ext_vector_type(2))) _Float16 f16x2;
typedef __attribute__((ext_vector_type(4))) unsigned int u32x4;
typedef __attribute__((ext_vector_type(4))) float f32x4;
typedef unsigned int uint32;
typedef unsigned short ushort;

__device__ __forceinline__ f16x2 u2h(uint32 u) {
    union { uint32 u; f16x2 h; } c; c.u = u; return c.h;
}
__device__ __forceinline__ f16x8 u2h8(u32x4 q) {
    union { u32x4 u; f16x8 h; } c; c.u = q; return c.h;
}

// asm-pinned 16B global loads. "=&v" early-clobber (R6 lesson).
#define GLOAD16(dst, a64) \
    asm volatile("global_load_dwordx4 %0, %1, off" : "=&v"(dst) : "v"(a64) : "memory")
#define WAITV(N) do { \
    asm volatile("s_waitcnt vmcnt(" #N ")" ::: "memory"); \
    __builtin_amdgcn_sched_barrier(0); } while (0)
#define DRAIN_ALL() do { \
    asm volatile("s_waitcnt vmcnt(0) lgkmcnt(0)" ::: "memory"); \
    __builtin_amdgcn_sched_barrier(0); } while (0)

// ---------------------------------------------------------------------------
// x [b][c][hw] f32  ->  xT [b][hw][c] f16   (LDS tile transpose)
// ---------------------------------------------------------------------------
__global__ __launch_bounds__(256) void transpose_x(
    const float* __restrict__ x, _Float16* __restrict__ xT)
{
    __shared__ float tile[64][65];
    int blk = blockIdx.x;
    int b   = blk >> 8;
    int hw0 = (blk & 255) * 64;
    int t   = threadIdx.x;
    int q   = t >> 6;
    int ln  = t & 63;
#pragma unroll
    for (int p = 0; p < 16; ++p) {
        int c = p * 4 + q;
        tile[c][ln] = x[((size_t)(b * C_ + c) << 14) + hw0 + ln];
    }
    __syncthreads();
#pragma unroll
    for (int p = 0; p < 16; ++p) {
        int hw = p * 4 + q;
        xT[(((size_t)b << 14) + hw0 + hw) * 64 + ln] = (_Float16)tile[ln][hw];
    }
}

// ---------------------------------------------------------------------------
// Weight fragments (f16).
// ---------------------------------------------------------------------------
__global__ __launch_bounds__(256) void prep3(
    const float* __restrict__ w_conv, const float* __restrict__ w_off,
    _Float16* __restrict__ wfrag, _Float16* __restrict__ wofff)
{
    int idx = blockIdx.x * 256 + threadIdx.x;
    if (idx < 36864) {
        int i    = idx & 7;
        int lane = (idx >> 3) & 63;
        int nb   = (idx >> 9) & 3;
        int kc   = (idx >> 11) & 1;
        int kk   = idx >> 12;
        int c = kc * 32 + ((lane >> 4) << 3) + i;
        int o = nb * 16 + (lane & 15);
        wfrag[idx] = (_Float16)w_conv[(o * C_ + c) * 9 + kk];
    }
    if (idx < 18432) {
        int i    = idx & 7;
        int lane = (idx >> 3) & 63;
        int nb   = (idx >> 9) & 1;
        int kc   = (idx >> 10) & 1;
        int kk   = idx >> 11;
        int m = nb * 16 + (lane & 15);
        int c = kc * 32 + ((lane >> 4) << 3) + i;
        wofff[idx] = (_Float16)((m < NOFF_) ? w_off[(m * C_ + c) * 9 + kk] : 0.0f);
    }
}

// ---------------------------------------------------------------------------
// Offset conv (R7-proven, unchanged).
// ---------------------------------------------------------------------------
__global__ __launch_bounds__(512, 2) void offconv_mfma5(
    const _Float16* __restrict__ xT, const _Float16* __restrict__ wofff,
    const float* __restrict__ b_off, _Float16* __restrict__ offsh)
{
    __shared__ _Float16 wlds[18432];
    int t = threadIdx.x;
    {
        const u32x4* src = (const u32x4*)wofff;
        u32x4* dst = (u32x4*)wlds;
#pragma unroll
        for (int r = 0; r < 5; ++r) {
            int i = r * 512 + t;
            if (i < 2304) dst[i] = src[i];
        }
    }
    DRAIN_ALL();
    __syncthreads();

    int blk  = blockIdx.x;
    int b    = blk & 7;
    int hw0  = (blk >> 3) * 128;
    int lane = t & 63;
    int wv   = t >> 6;
    int pxb  = hw0 + wv * 16;
    int pr   = lane & 15;
    int g    = lane >> 4;
    int px   = pxb + pr;
    int h = px >> 7, w = px & (W_ - 1);
    const _Float16* xb = xT + (((size_t)b << 14) << 6);

    f32x4 acc[2];
#pragma unroll
    for (int nb = 0; nb < 2; ++nb) acc[nb] = (f32x4){0.f, 0.f, 0.f, 0.f};

    u32x4 q[3][2];
    bool  vld[3];

    auto issueO = [&](int kk, int st) {
        int ky = kk / 3, kx = kk % 3;
        int yy = h - 1 + ky, xx = w - 1 + kx;
        vld[st] = ((unsigned)yy < (unsigned)H_) && ((unsigned)xx < (unsigned)W_);
        int src = (min(max(yy, 0), H_ - 1) << 7) + min(max(xx, 0), W_ - 1);
        unsigned long long a = (unsigned long long)(xb + ((size_t)src << 6) + g * 8);
        GLOAD16(q[st][0], a);
        unsigned long long a2 = a + 64;
        GLOAD16(q[st][1], a2);
    };

    issueO(0, 0); issueO(1, 1); issueO(2, 2);
#pragma unroll
    for (int kk = 0; kk < KK_; ++kk) {
        const int s = kk % 3;
        if (kk < 7)      { WAITV(4); }
        else if (kk < 8) { WAITV(2); }
        else             { WAITV(0); }
#pragma unroll
        for (int kc = 0; kc < 2; ++kc) {
            f16x8 a = u2h8(q[s][kc]);
            f16x8 z = {};
            a = vld[s] ? a : z;
#pragma unroll
            for (int nb = 0; nb < 2; ++nb) {
                f16x8 bfr = *(const f16x8*)(wlds +
                    ((((kk * 2 + kc) << 1) + nb) << 9) + (lane << 3));
                acc[nb] = __builtin_amdgcn_mfma_f32_16x16x32_f16(a, bfr, acc[nb], 0, 0, 0);
            }
        }
        if (kk < 6) issueO(kk + 3, s);
    }

#pragma unroll
    for (int nb = 0; nb < 2; ++nb) {
        int m = nb * 16 + pr;
        if (m < NOFF_) {
            float bias = b_off[m];
#pragma unroll
            for (int r = 0; r < 4; ++r) {
                int prow = pxb + g * 4 + r;
                offsh[(size_t)((b << 14) + prow) * NOFF_ + m] = (_Float16)(acc[nb][r] + bias);
            }
        }
    }
}

// ---------------------------------------------------------------------------
// Deformable conv R10: 8x8-px blocks; clamped 19x19 NHWC x-neighborhood staged
// in 46.2 KB swizzled LDS (3 blocks/CU). Per kk each lane ds_read_b128's its
// own fragment corner chunks (conflict-free by XOR swizzle), bilerps in-lane,
// feeds MFMA. Rare out-of-window samples (|d|>~4): wave-uniform fallback to
// global gathers. All weights streamed from global, WAITV(0) per kk.
// ---------------------------------------------------------------------------
__global__ __launch_bounds__(256, 3) void deform_mfma9(
    const _Float16* __restrict__ xT, const _Float16* __restrict__ offsh,
    const _Float16* __restrict__ wfrag, float* __restrict__ out)
{
    __shared__ u32x4 tile4[TW_ * TW_ * 8];    // 46,208 B

    int t    = threadIdx.x;
    int blk  = blockIdx.x;
    int b    = blk & 7;                       // XCD-aligned batch
    int tid  = blk >> 3;                      // 0..255 tile id
    int ty   = tid >> 4, tx = tid & 15;
    int lane = t & 63;
    int wv   = t >> 6;
    int pr   = lane & 15;                     // fragment px row
    int gg   = lane >> 4;                     // fragment k-group
    int ry0  = ty * 8 - PADW_;
    int cx0  = tx * 8 - PADW_;
    const _Float16* xb = xT + (((size_t)b << 14) << 6);

    // ---- stage clamped 19x19 neighborhood (coalesced, swizzled) ----
#pragma unroll
    for (int it = 0; it < 12; ++it) {
        int idx = it * 256 + t;
        if (idx < TW_ * TW_ * 8) {
            int i   = idx / (TW_ * 8);
            int rem = idx - i * (TW_ * 8);
            int j   = rem >> 3, cg = rem & 7;
            int yy = min(max(ry0 + i, 0), H_ - 1);
            int xx = min(max(cx0 + j, 0), W_ - 1);
            u32x4 v = *(const u32x4*)(xb + (((size_t)((yy << 7) + xx)) << 6) + (cg << 3));
            int rl = i * TW_ + j;
            int bo = ((rl << 7) + (cg << 4)) ^ ((rl & 7) << 4);
            *(u32x4*)((char*)tile4 + bo) = v;
        }
    }

    // per-lane pixel (fragment role) + its 9 offset pairs
    int h_img = ty * 8 + wv * 2 + (pr >> 3);
    int w_img = tx * 8 + (pr & 7);
    const uint32* obu = (const uint32*)(offsh +
        (size_t)((b << 14) + (h_img << 7) + w_img) * NOFF_);
    uint32 dpk[9];
#pragma unroll
    for (int kk = 0; kk < 9; ++kk) dpk[kk] = obu[kk];
    DRAIN_ALL();
    __syncthreads();

    f32x4 acc[4];
#pragma unroll
    for (int nb = 0; nb < 4; ++nb) acc[nb] = (f32x4){0.f, 0.f, 0.f, 0.f};

    u32x4 wq[8];        // streamed weights for current kk
    u32x4 q[8];         // corner data [kc*4 + corner]

#pragma unroll
    for (int kk = 0; kk < KK_; ++kk) {
        // 1. stream this kk's weight frags (coalesced 1KB loads)
#pragma unroll
        for (int f = 0; f < 8; ++f) {         // f = kc*4 + nb
            unsigned long long wa = (unsigned long long)(wfrag +
                ((((kk * 2 + (f >> 2)) << 2) + (f & 3)) << 9) + (lane << 3));
            GLOAD16(wq[f], wa);
        }

        // 2. bilinear prep for this lane's own pixel
        int ky = kk / 3, kx = kk % 3;
        union { uint32 u; f16x2 hh; } cv; cv.u = dpk[kk];
        float dyv = (float)cv.hh[0], dxv = (float)cv.hh[1];
        float py  = (float)(h_img - 1 + ky) + dyv;
        float pxf = (float)(w_img - 1 + kx) + dxv;
        float y0f = floorf(py), x0f = floorf(pxf);
        float ly = py - y0f, lx = pxf - x0f;
        int y0 = (int)y0f, x0 = (int)x0f;
        float w00 = (1.f - ly) * (1.f - lx);
        float w01 = (1.f - ly) * lx;
        float w10 = ly * (1.f - lx);
        float w11 = ly * lx;
        bool vy0 = (unsigned)y0       < (unsigned)H_;
        bool vy1 = (unsigned)(y0 + 1) < (unsigned)H_;
        bool vx0 = (unsigned)x0       < (unsigned)W_;
        bool vx1 = (unsigned)(x0 + 1) < (unsigned)W_;
        if (!(vy0 && vx0)) w00 = 0.f;
        if (!(vy0 && vx1)) w01 = 0.f;
        if (!(vy1 && vx0)) w10 = 0.f;
        if (!(vy1 && vx1)) w11 = 0.f;
        int yc0 = min(max(y0, 0), H_ - 1);
        int yc1 = min(max(y0 + 1, 0), H_ - 1);
        int xc0 = min(max(x0, 0), W_ - 1);
        int xc1 = min(max(x0 + 1, 0), W_ - 1);
        f16x2 Wc0 = (f16x2){(_Float16)w00, (_Float16)w00};
        f16x2 Wc1 = (f16x2){(_Float16)w01, (_Float16)w01};
        f16x2 Wc2 = (f16x2){(_Float16)w10, (_Float16)w10};
        f16x2 Wc3 = (f16x2){(_Float16)w11, (_Float16)w11};

        int r0 = yc0 - ry0, r1 = yc1 - ry0;
        int c0 = xc0 - cx0, c1 = xc1 - cx0;
        int bad = ((unsigned)r0 >= TW_) | ((unsigned)r1 >= TW_) |
                  ((unsigned)c0 >= TW_) | ((unsigned)c1 >= TW_);

        if (!__any(bad)) {
            // 3a. LDS gather: own corner chunks (swizzled, conflict-free)
            int rl00 = r0 * TW_ + c0, rl01 = r0 * TW_ + c1;
            int rl10 = r1 * TW_ + c0, rl11 = r1 * TW_ + c1;
#pragma unroll
            for (int kc = 0; kc < 2; ++kc) {
                int ch = ((kc << 2) + gg) << 4;   // chunk byte offset
                q[kc * 4 + 0] = *(const u32x4*)((char*)tile4 + (((rl00 << 7) + ch) ^ ((rl00 & 7) << 4)));
                q[kc * 4 + 1] = *(const u32x4*)((char*)tile4 + (((rl01 << 7) + ch) ^ ((rl01 & 7) << 4)));
                q[kc * 4 + 2] = *(const u32x4*)((char*)tile4 + (((rl10 << 7) + ch) ^ ((rl10 & 7) << 4)));
                q[kc * 4 + 3] = *(const u32x4*)((char*)tile4 + (((rl11 << 7) + ch) ^ ((rl11 & 7) << 4)));
            }
        } else {
            // 3b. rare fallback: global gathers (clamped), drained by WAITV(0)
#pragma unroll
            for (int kc = 0; kc < 2; ++kc) {
                int ce = ((kc << 2) + gg) << 3;   // chunk element offset
                unsigned long long a00 = (unsigned long long)(xb + (((size_t)((yc0 << 7) + xc0)) << 6) + ce);
                unsigned long long a01 = (unsigned long long)(xb + (((size_t)((yc0 << 7) + xc1)) << 6) + ce);
                unsigned long long a10 = (unsigned long long)(xb + (((size_t)((yc1 << 7) + xc0)) << 6) + ce);
                unsigned long long a11 = (unsigned long long)(xb + (((size_t)((yc1 << 7) + xc1)) << 6) + ce);
                GLOAD16(q[kc * 4 + 0], a00);
                GLOAD16(q[kc * 4 + 1], a01);
                GLOAD16(q[kc * 4 + 2], a10);
                GLOAD16(q[kc * 4 + 3], a11);
            }
        }

        WAITV(0);    // weights (and fallback gathers) complete

        // 4. bilerp + MFMA
#pragma unroll
        for (int kc = 0; kc < 2; ++kc) {
            f16x8 a;
            f16x2* ap = (f16x2*)&a;
#pragma unroll
            for (int p4 = 0; p4 < 4; ++p4) {
                ap[p4] = u2h(q[kc * 4 + 0][p4]) * Wc0
                       + u2h(q[kc * 4 + 1][p4]) * Wc1
                       + u2h(q[kc * 4 + 2][p4]) * Wc2
                       + u2h(q[kc * 4 + 3][p4]) * Wc3;
            }
#pragma unroll
            for (int nb = 0; nb < 4; ++nb) {
                acc[nb] = __builtin_amdgcn_mfma_f32_16x16x32_f16(
                    a, u2h8(wq[kc * 4 + nb]), acc[nb], 0, 0, 0);
            }
        }
    }

    // C/D: col=lane&15 -> o; row=gg*4+r -> p_local -> (row pair, col quad)
#pragma unroll
    for (int nb = 0; nb < 4; ++nb) {
        int o = nb * 16 + pr;
        int orow = ty * 8 + wv * 2 + (gg >> 1);
        int ocol = tx * 8 + ((gg & 1) << 2);
        float* outp = out + (((size_t)(b * O_ + o)) << 14) + (orow << 7) + ocol;
        *(f32x4*)outp = acc[nb];
    }
}

// ===========================================================================
extern "C" void kernel_launch(void* const* d_in, const int* in_sizes, int n_in,
                              void* d_out, int out_size, void* d_ws, size_t ws_size,
                              hipStream_t stream)
{
    const float* x      = (const float*)d_in[0];
    const float* w_off  = (const float*)d_in[1];
    const float* b_off  = (const float*)d_in[2];
    const float* w_conv = (const float*)d_in[3];
    float* out = (float*)d_out;
    char* ws = (char*)d_ws;

    // workspace layout (bytes) — total 21,643,264
    const size_t XT_OFF    = 0;           // 16,777,216  f16 NHWC x
    const size_t OFFS_OFF  = 16777216;    //  4,718,592  f16 NHWC offsets
    const size_t WFRAG_OFF = 21495808;    //     73,728  deform weight frags
    const size_t WOFF_OFF  = 21569536;    //     36,864  offset weight frags

    _Float16* xT    = (_Float16*)(ws + XT_OFF);
    _Float16* offsh = (_Float16*)(ws + OFFS_OFF);
    _Float16* wfrag = (_Float16*)(ws + WFRAG_OFF);
    _Float16* wofff = (_Float16*)(ws + WOFF_OFF);

    transpose_x  <<<2048, 256, 0, stream>>>(x, xT);
    prep3        <<<144, 256, 0, stream>>>(w_conv, w_off, wfrag, wofff);
    offconv_mfma5<<<1024, 512, 0, stream>>>(xT, wofff, b_off, offsh);
    deform_mfma9 <<<2048, 256, 0, stream>>>(xT, offsh, wfrag, out);
}